// Round 2
// baseline (29590.720 us; speedup 1.0000x reference)
//
#include <hip/hip_runtime.h>
#include <hip/hip_bf16.h>
#include <math.h>

// x:(2048,3,32,32) f32; idx; w1:(128,3,4,4); b1:(128); w2:(256,128,4,4); b2:(256)
// cb0/cb1/cb2:(512,256); fc1_w:(512,16384); fc1_b:(512); fc2_w:(10,512); fc2_b:(10)
// out: 2048*10 logits ++ loss ++ perplexity = 20482 f32
// Workspace budget is unknown -> keep total < ~110 MB (round-1 abort was most
// consistent with ws overflow at 536 MB). Batch processed in 8 chunks of 256.

#define CHUNK 256
#define NCH 8

// ---------------- conv1: (256,3,32,32) -> relu -> h (256,128,16,16) ----------------
__global__ __launch_bounds__(256) void k_conv1(const float* __restrict__ x,
                                               const float* __restrict__ w1,
                                               const float* __restrict__ b1,
                                               float* __restrict__ h) {
    __shared__ float xs[3 * 32 * 32];
    int b = blockIdx.x;                       // chunk-local image
    const float* xb = x + (size_t)b * 3072;
    for (int i = threadIdx.x; i < 768; i += 256)
        ((float4*)xs)[i] = ((const float4*)xb)[i];
    __syncthreads();
    int t = threadIdx.x;
    int py = t >> 4, px = t & 15;
    float win[48];
#pragma unroll
    for (int ci = 0; ci < 3; ci++)
#pragma unroll
        for (int ky = 0; ky < 4; ky++) {
            int iy = 2 * py - 1 + ky;
#pragma unroll
            for (int kx = 0; kx < 4; kx++) {
                int ix = 2 * px - 1 + kx;
                bool ok = ((unsigned)iy < 32u) && ((unsigned)ix < 32u);
                win[ci * 16 + ky * 4 + kx] = ok ? xs[ci * 1024 + iy * 32 + ix] : 0.f;
            }
        }
    float* hb = h + (size_t)b * 32768;
    for (int co = 0; co < 128; co++) {
        const float* w = w1 + co * 48;        // wave-uniform -> scalar loads
        float acc = b1[co];
#pragma unroll
        for (int q = 0; q < 48; q++) acc = fmaf(win[q], w[q], acc);
        hb[co * 256 + t] = fmaxf(acc, 0.f);
    }
}

// ---------------- conv2: h (256,128,16,16) -> relu -> fea (256,256,8,8) ----------------
__global__ __launch_bounds__(256) void k_conv2(const float* __restrict__ h,
                                               const float* __restrict__ w2,
                                               const float* __restrict__ b2,
                                               float* __restrict__ fea) {
    __shared__ float hs[8 * 256];
    int b = blockIdx.x;
    int cg = blockIdx.y;                      // 0..3 out-channel group
    int t = threadIdx.x;
    int p = t & 63;
    int g = __builtin_amdgcn_readfirstlane(t >> 6);
    int yo = p >> 3, xo = p & 7;
    int cobase = cg * 64 + g * 16;
    float acc[16];
#pragma unroll
    for (int j = 0; j < 16; j++) acc[j] = b2[cobase + j];
    const float* hb = h + (size_t)b * 32768;
    for (int c0 = 0; c0 < 128; c0 += 8) {
        __syncthreads();
        {
            const float4* src = (const float4*)(hb + c0 * 256);
            float4* dst = (float4*)hs;
            dst[t] = src[t];
            dst[t + 256] = src[t + 256];
        }
        __syncthreads();
#pragma unroll
        for (int cl = 0; cl < 8; cl++) {
            float tv[16];
#pragma unroll
            for (int ky = 0; ky < 4; ky++) {
                int iy = 2 * yo - 1 + ky;
                bool yok = (unsigned)iy < 16u;
#pragma unroll
                for (int kx = 0; kx < 4; kx++) {
                    int ix = 2 * xo - 1 + kx;
                    bool ok = yok && ((unsigned)ix < 16u);
                    tv[ky * 4 + kx] = ok ? hs[cl * 256 + iy * 16 + ix] : 0.f;
                }
            }
#pragma unroll
            for (int j = 0; j < 16; j++) {
                const float* w = w2 + ((size_t)(cobase + j) * 128 + (c0 + cl)) * 16;
                float part = 0.f;
#pragma unroll
                for (int q = 0; q < 16; q++) part = fmaf(tv[q], w[q], part);
                acc[j] += part;               // short chains: f32 err ~1e-7
            }
        }
    }
    float* fb = fea + (size_t)b * 16384 + (size_t)cobase * 64;
#pragma unroll
    for (int j = 0; j < 16; j++) fb[j * 64 + p] = fmaxf(acc[j], 0.f);
}

// ---------------- combined codebook: rows 0-511 = cb0, 512-1023 = cb_idx ----------------
__global__ __launch_bounds__(256) void k_comb(const float* __restrict__ cb0,
                                              const float* __restrict__ cb1,
                                              const float* __restrict__ cb2,
                                              const int* __restrict__ idxp,
                                              float* __restrict__ C) {
    int i = blockIdx.x * 256 + threadIdx.x;   // float4 id, 65536 total
    int idx = *idxp;
    const float4* lo = (const float4*)cb0;
    const float4* hi = (const float4*)((idx == 2) ? cb2 : ((idx == 1) ? cb1 : cb0));
    ((float4*)C)[i] = (i < 32768) ? lo[i] : hi[i - 32768];
}

// ---------------- half code norms (f64-exact, stored f32) ----------------
__global__ __launch_bounds__(256) void k_cnorm(const float* __restrict__ C,
                                               const int* __restrict__ idxp,
                                               float* __restrict__ cnorm) {
    int c = blockIdx.x * 256 + threadIdx.x;
    int Kc = (*idxp == 0) ? 512 : 1024;
    if (c >= 1024) return;
    if (c >= Kc) { cnorm[c] = 3.0e38f; return; }
    const float* row = C + (size_t)c * 256;
    double s = 0.0;
    for (int d = 0; d < 256; d++) { double v = row[d]; s += v * v; }
    cnorm[c] = (float)(0.5 * s);
}

// ---------------- VQ screening: top-2 per (row, wave-group) -> 8 candidates ----------------
__global__ __launch_bounds__(256) void k_vq(const float* __restrict__ fea,
                                            const float* __restrict__ C,
                                            const float* __restrict__ cnorm,
                                            const int* __restrict__ idxp,
                                            int* __restrict__ cand) {
    __shared__ float xs[16384];               // 64 KB: [d][p]
    int b = blockIdx.x, t = threadIdx.x;
    const float* fb = fea + (size_t)b * 16384;
    for (int i = t; i < 4096; i += 256)
        ((float4*)xs)[i] = ((const float4*)fb)[i];
    __syncthreads();
    int Kc = (*idxp == 0) ? 512 : 1024;
    int p = t & 63;
    int g = __builtin_amdgcn_readfirstlane(t >> 6);
    float min1 = 3.0e38f, min2 = 3.1e38f;
    int i1 = 0, i2 = 1;
    int npg = Kc >> 2;
    for (int cc = 0; cc < npg; cc += 8) {
        float s[8];
        int cidx[8];
#pragma unroll
        for (int j = 0; j < 8; j++) {
            int c = (cc + j) * 4 + g;         // wave-uniform
            cidx[j] = c;
            s[j] = cnorm[c];
        }
        for (int d0 = 0; d0 < 256; d0 += 16) {
            float xv[16];
#pragma unroll
            for (int q = 0; q < 16; q++) xv[q] = xs[(d0 + q) * 64 + p];
#pragma unroll
            for (int j = 0; j < 8; j++) {
                const float* row = C + (size_t)cidx[j] * 256 + d0;  // uniform
#pragma unroll
                for (int q = 0; q < 16; q++) s[j] = fmaf(-xv[q], row[q], s[j]);
            }
        }
#pragma unroll
        for (int j = 0; j < 8; j++) {
            float v = s[j];
            if (v < min1) { min2 = min1; i2 = i1; min1 = v; i1 = cidx[j]; }
            else if (v < min2) { min2 = v; i2 = cidx[j]; }
        }
    }
    size_t r = (size_t)b * 64 + p;
    cand[r * 8 + g * 2 + 0] = i1;
    cand[r * 8 + g * 2 + 1] = i2;
}

// ---------------- exact f64 rescore of 8 candidates; best dist IS the loss term ----------------
__global__ __launch_bounds__(256) void k_rescore(const float* __restrict__ fea,
                                                 const float* __restrict__ C,
                                                 const int* __restrict__ cand,
                                                 int* __restrict__ enc,
                                                 double* __restrict__ dloss) {
    __shared__ double dsm[256];
    __shared__ int dim_[256];
    __shared__ double bsum[32];
    int t = threadIdx.x;
    int rr = blockIdx.x * 32 + (t >> 3);      // chunk-local row
    int j = t & 7;
    int c = cand[(size_t)rr * 8 + j];
    const float* row = C + (size_t)c * 256;
    int bl = rr >> 6, p = rr & 63;
    const float* xrow = fea + (size_t)bl * 16384 + p;
    double s = 0.0;
    for (int d = 0; d < 256; d++) {
        double diff = (double)xrow[d * 64] - (double)row[d];
        s = fma(diff, diff, s);
    }
    dsm[t] = s;
    dim_[t] = c;
    __syncthreads();
    if (j == 0) {
        double best = dsm[t]; int bi = dim_[t];
        for (int q = 1; q < 8; q++) {
            double v = dsm[t + q]; int ci = dim_[t + q];
            if (v < best || (v == best && ci < bi)) { best = v; bi = ci; }
        }
        enc[rr] = bi;
        bsum[t >> 3] = best;                  // loss = sum of best dists
    }
    __syncthreads();
    if (t == 0) {
        double acc = 0.0;
        for (int q = 0; q < 32; q++) acc += bsum[q];
        atomicAdd(dloss, acc);
    }
}

// ---------------- histogram ----------------
__global__ __launch_bounds__(256) void k_hist(const int* __restrict__ enc,
                                              int* __restrict__ counts) {
    __shared__ int hc[1024];
    for (int i = threadIdx.x; i < 1024; i += 256) hc[i] = 0;
    __syncthreads();
    int base = blockIdx.x * 1024;
    for (int i = threadIdx.x; i < 1024; i += 256) atomicAdd(&hc[enc[base + i]], 1);
    __syncthreads();
    for (int i = threadIdx.x; i < 1024; i += 256)
        if (hc[i]) atomicAdd(&counts[i], hc[i]);
}

// ---------------- Wt[n][p][d] = fc1_w[n][d*64+p]  (one-time transpose) ----------------
__global__ __launch_bounds__(256) void k_wt(const float* __restrict__ W,
                                            float* __restrict__ Wt) {
    __shared__ float tile[64][65];
    int n = blockIdx.x;
    int d0 = blockIdx.y * 64;
    int t = threadIdx.x;
    const float* src = W + (size_t)n * 16384 + (size_t)d0 * 64;   // 4096 consecutive
#pragma unroll
    for (int u = 0; u < 4; u++) {
        int i = t + u * 256;                  // float4 id 0..1023
        float4 v = ((const float4*)src)[i];
        int dd = i >> 4;
        int p = (i & 15) << 2;
        tile[dd][p] = v.x; tile[dd][p + 1] = v.y; tile[dd][p + 2] = v.z; tile[dd][p + 3] = v.w;
    }
    __syncthreads();
    float* dst = Wt + (size_t)n * 16384 + d0;
#pragma unroll
    for (int u = 0; u < 4; u++) {
        int i = t + u * 256;
        int p = i >> 4;
        int dd = (i & 15) << 2;
        float4 v = { tile[dd][p], tile[dd + 1][p], tile[dd + 2][p], tile[dd + 3][p] };
        *(float4*)(dst + (size_t)p * 256 + dd) = v;
    }
}

// ---------------- fc1 GEMM with gathered A:  A[m][(p,d)] = C[enc[m*64+p]][d] ----------------
// out[m][n] = sum_p sum_d C[e_{m,p}][d] * Wt[n][p][d];   split-K over p (4 slices of 16)
__global__ __launch_bounds__(256) void k_fc1g(const int* __restrict__ enc,
                                              const float* __restrict__ C,
                                              const float* __restrict__ Wt,
                                              float* __restrict__ part) {
    __shared__ float As[32][132];
    __shared__ float Bs[32][132];
    __shared__ int encs[128];
    int t = threadIdx.x;
    int m0 = blockIdx.x * 128, n0 = blockIdx.y * 128;
    int ty = t >> 4, tx = t & 15;
    float acc[8][8];
#pragma unroll
    for (int i = 0; i < 8; i++)
#pragma unroll
        for (int j = 0; j < 8; j++) acc[i][j] = 0.f;
    int p0 = blockIdx.z * 16;
    for (int p = p0; p < p0 + 16; p++) {
        __syncthreads();
        if (t < 128) encs[t] = enc[(size_t)(m0 + t) * 64 + p];
        __syncthreads();
        for (int dc = 0; dc < 256; dc += 32) {
#pragma unroll
            for (int u = 0; u < 4; u++) {
                int i = t + u * 256;
                int row = i >> 3, kq = (i & 7) << 2;
                float4 v = *(const float4*)(C + (size_t)encs[row] * 256 + dc + kq);
                As[kq + 0][row] = v.x; As[kq + 1][row] = v.y;
                As[kq + 2][row] = v.z; As[kq + 3][row] = v.w;
                float4 wv = *(const float4*)(Wt + (size_t)(n0 + row) * 16384 + p * 256 + dc + kq);
                Bs[kq + 0][row] = wv.x; Bs[kq + 1][row] = wv.y;
                Bs[kq + 2][row] = wv.z; Bs[kq + 3][row] = wv.w;
            }
            __syncthreads();
#pragma unroll
            for (int k = 0; k < 32; k++) {
                float a[8], bv[8];
                *(float4*)(a)      = *(const float4*)&As[k][ty * 8];
                *(float4*)(a + 4)  = *(const float4*)&As[k][ty * 8 + 4];
                *(float4*)(bv)     = *(const float4*)&Bs[k][tx * 8];
                *(float4*)(bv + 4) = *(const float4*)&Bs[k][tx * 8 + 4];
#pragma unroll
                for (int i = 0; i < 8; i++)
#pragma unroll
                    for (int j = 0; j < 8; j++) acc[i][j] = fmaf(a[i], bv[j], acc[i][j]);
            }
            __syncthreads();
        }
    }
    float* P = part + (size_t)blockIdx.z * (2048 * 512);
#pragma unroll
    for (int i = 0; i < 8; i++)
#pragma unroll
        for (int j = 0; j < 8; j++)
            P[(size_t)(m0 + ty * 8 + i) * 512 + (n0 + tx * 8 + j)] = acc[i][j];
}

__global__ __launch_bounds__(256) void k_fc1fin(const float* __restrict__ part,
                                                const float* __restrict__ bias,
                                                float* __restrict__ h1) {
    int i = blockIdx.x * 256 + threadIdx.x;   // < 1048576
    float s = part[i] + part[i + 1048576] + part[i + 2097152] + part[i + 3145728];
    s += bias[i & 511];
    h1[i] = 0.5f * s * (1.f + erff(s * 0.70710678118654752f));   // exact gelu
}

// ---------------- fc2 ----------------
__global__ __launch_bounds__(256) void k_fc2(const float* __restrict__ h1,
                                             const float* __restrict__ w,
                                             const float* __restrict__ bias,
                                             float* __restrict__ out) {
    int gid = blockIdx.x * 256 + threadIdx.x;
    if (gid >= 20480) return;
    int b = gid / 10, k = gid % 10;
    const float* hr = h1 + (size_t)b * 512;
    const float* wr = w + (size_t)k * 512;
    float acc = bias[k];
#pragma unroll 8
    for (int j = 0; j < 512; j++) acc = fmaf(hr[j], wr[j], acc);
    out[gid] = acc;
}

// ---------------- loss + perplexity ----------------
__global__ __launch_bounds__(256) void k_final(const int* __restrict__ counts,
                                               const double* __restrict__ dloss,
                                               const int* __restrict__ idxp,
                                               float* __restrict__ out) {
    __shared__ float sb[256];
    int t = threadIdx.x;
    int Kc = (*idxp == 0) ? 512 : 1024;
    float local = 0.f;
    for (int c = t; c < Kc; c += 256) {
        float pr = (float)counts[c] * (1.0f / 131072.0f);
        local += pr * logf(pr + 1e-10f);
    }
    sb[t] = local;
    __syncthreads();
    for (int o = 128; o > 0; o >>= 1) {
        if (t < o) sb[t] += sb[t + o];
        __syncthreads();
    }
    if (t == 0) {
        // q_latent == e_latent numerically -> loss = 1.25 * mean((q-x)^2)
        out[20480] = (float)(dloss[0] * 1.25 / (131072.0 * 256.0));
        out[20481] = expf(-sb[0]);
    }
}

extern "C" void kernel_launch(void* const* d_in, const int* in_sizes, int n_in,
                              void* d_out, int out_size, void* d_ws, size_t ws_size,
                              hipStream_t stream) {
    const float* x    = (const float*)d_in[0];
    const int*   idxp = (const int*)d_in[1];
    const float* w1   = (const float*)d_in[2];
    const float* b1   = (const float*)d_in[3];
    const float* w2   = (const float*)d_in[4];
    const float* b2   = (const float*)d_in[5];
    const float* cb0  = (const float*)d_in[6];
    const float* cb1  = (const float*)d_in[7];
    const float* cb2  = (const float*)d_in[8];
    const float* fc1w = (const float*)d_in[9];
    const float* fc1b = (const float*)d_in[10];
    const float* fc2w = (const float*)d_in[11];
    const float* fc2b = (const float*)d_in[12];
    float* out = (float*)d_out;

    char* ws = (char*)d_ws;
    size_t off = 0;
    float* h_c   = (float*)(ws + off); off += (size_t)CHUNK * 32768 * 4;   // 33.6 MB
    float* fea_c = (float*)(ws + off); off += (size_t)CHUNK * 16384 * 4;   // 16.8 MB
    float* Wt    = (float*)(ws + off); off += (size_t)512 * 16384 * 4;     // 33.6 MB
    float* Cc    = (float*)(ws + off); off += (size_t)1024 * 256 * 4;      //  1.0 MB
    float* part  = (float*)(ws + off); off += (size_t)4 * 2048 * 512 * 4;  // 16.8 MB
    float* h1    = (float*)(ws + off); off += (size_t)2048 * 512 * 4;      //  4.2 MB
    int*   cand  = (int*)(ws + off);   off += (size_t)CHUNK * 64 * 8 * 4;  //  0.5 MB
    int*   enc   = (int*)(ws + off);   off += (size_t)131072 * 4;          //  0.5 MB
    float* cnorm = (float*)(ws + off); off += 1024 * 4;
    int*   counts= (int*)(ws + off);   off += 1024 * 4;
    double* dloss= (double*)(ws + off); off += 8;
    // total ~107 MB

    hipMemsetAsync(counts, 0, 1024 * 4 + 8, stream);   // counts + dloss (contiguous)

    k_comb<<<256, 256, 0, stream>>>(cb0, cb1, cb2, idxp, Cc);
    k_cnorm<<<4, 256, 0, stream>>>(Cc, idxp, cnorm);
    k_wt<<<dim3(512, 4), 256, 0, stream>>>(fc1w, Wt);

    for (int c = 0; c < NCH; c++) {
        k_conv1<<<CHUNK, 256, 0, stream>>>(x + (size_t)c * CHUNK * 3072, w1, b1, h_c);
        k_conv2<<<dim3(CHUNK, 4), 256, 0, stream>>>(h_c, w2, b2, fea_c);
        k_vq<<<CHUNK, 256, 0, stream>>>(fea_c, Cc, cnorm, idxp, cand);
        k_rescore<<<(CHUNK * 64) / 32, 256, 0, stream>>>(fea_c, Cc, cand,
                                                         enc + (size_t)c * CHUNK * 64, dloss);
    }

    k_hist<<<128, 256, 0, stream>>>(enc, counts);
    k_fc1g<<<dim3(16, 4, 4), 256, 0, stream>>>(enc, Cc, Wt, part);
    k_fc1fin<<<4096, 256, 0, stream>>>(part, fc1b, h1);
    k_fc2<<<80, 256, 0, stream>>>(h1, fc2w, fc2b, out);
    k_final<<<1, 256, 0, stream>>>(counts, dloss, idxp, out);
}

// Round 3
// 10230.736 us; speedup vs baseline: 2.8923x; 2.8923x over previous
//
#include <hip/hip_runtime.h>
#include <hip/hip_bf16.h>
#include <math.h>

// x:(2048,3,32,32) f32; idx; w1:(128,3,4,4); b1:(128); w2:(256,128,4,4); b2:(256)
// cb0/cb1/cb2:(512,256); fc1_w:(512,16384); fc1_b:(512); fc2_w:(10,512); fc2_b:(10)
// out: 2048*10 logits ++ loss ++ perplexity = 20482 f32
// ws kept < ~110 MB (ws cap unknown; 107 MB passed in round 2).

#define CHUNK 256
#define NCH 8

// ---------------- conv1: (256,3,32,32) -> relu -> h (256,128,16,16) ----------------
// R2 disease fix: w1/b1 staged in LDS (broadcast b128 reads) instead of per-wave
// global loads in the co-loop.
__global__ __launch_bounds__(256) void k_conv1(const float* __restrict__ x,
                                               const float* __restrict__ w1,
                                               const float* __restrict__ b1,
                                               float* __restrict__ h) {
    __shared__ float xs[3 * 32 * 32];
    __shared__ float w1s[128 * 48];
    __shared__ float b1s[128];
    int b = blockIdx.x, t = threadIdx.x;
    const float* xb = x + (size_t)b * 3072;
    for (int i = t; i < 768; i += 256)
        ((float4*)xs)[i] = ((const float4*)xb)[i];
    for (int i = t; i < 1536; i += 256)
        ((float4*)w1s)[i] = ((const float4*)w1)[i];
    if (t < 128) b1s[t] = b1[t];
    __syncthreads();
    int py = t >> 4, px = t & 15;
    float win[48];
#pragma unroll
    for (int ci = 0; ci < 3; ci++)
#pragma unroll
        for (int ky = 0; ky < 4; ky++) {
            int iy = 2 * py - 1 + ky;
#pragma unroll
            for (int kx = 0; kx < 4; kx++) {
                int ix = 2 * px - 1 + kx;
                bool ok = ((unsigned)iy < 32u) && ((unsigned)ix < 32u);
                win[ci * 16 + ky * 4 + kx] = ok ? xs[ci * 1024 + iy * 32 + ix] : 0.f;
            }
        }
    float* hb = h + (size_t)b * 32768;
    for (int co = 0; co < 128; co++) {
        float acc = b1s[co];
#pragma unroll
        for (int q = 0; q < 12; q++) {
            float4 w = *(const float4*)&w1s[co * 48 + q * 4];   // uniform -> broadcast
            acc = fmaf(win[q * 4 + 0], w.x, acc);
            acc = fmaf(win[q * 4 + 1], w.y, acc);
            acc = fmaf(win[q * 4 + 2], w.z, acc);
            acc = fmaf(win[q * 4 + 3], w.w, acc);
        }
        hb[co * 256 + t] = fmaxf(acc, 0.f);
    }
}

// ---------------- conv2 v2: implicit GEMM with LDS-staged weights ----------------
// grid (CHUNK, 8): block = (image, group of 32 out-channels). 256 threads:
// lane l: yo = l&7 (output row), c8 = l>>3 (co within wave); wave g -> co = cg*32+g*8+c8.
// Each thread: acc[8] over xo. Per (ci, ky): read padded h-row (20 floats, 5x b128,
// conflict-free: 8 unique addrs x 8-lane broadcast) + 1 broadcast b128 of weights.
__global__ __launch_bounds__(256) void k_conv2(const float* __restrict__ h,
                                               const float* __restrict__ w2,
                                               const float* __restrict__ b2,
                                               float* __restrict__ fea) {
    __shared__ float hs[8 * 18 * 20];   // [cl][iy+1 0..17][ix+1 0..19], borders zero
    __shared__ float wl[32 * 132];      // [co_local][128k], pad 132 -> broadcast quads spread banks
    int b = blockIdx.x, cg = blockIdx.y, t = threadIdx.x;
    int l = t & 63;
    int g = __builtin_amdgcn_readfirstlane(t >> 6);
    int yo = l & 7, c8 = l >> 3;
    int cw = g * 8 + c8;                // 0..31
    int co = cg * 32 + cw;
    for (int i = t; i < 2880; i += 256) hs[i] = 0.f;   // borders stay zero forever
    float bb = b2[co];
    float acc[8];
#pragma unroll
    for (int j = 0; j < 8; j++) acc[j] = 0.f;
    const float* hb = h + (size_t)b * 32768;
    for (int c0 = 0; c0 < 128; c0 += 8) {
        __syncthreads();
        // stage h slice: 8 ci x 16x16, into padded rows (interior fully rewritten)
#pragma unroll
        for (int u = 0; u < 2; u++) {
            int i = t + u * 256;                    // float4 id 0..511
            int cl = i >> 6, r = (i >> 2) & 15, q = i & 3;
            float4 v = ((const float4*)(hb + (size_t)(c0 + cl) * 256))[(r << 2) + q];
            float* dst = &hs[cl * 360 + (r + 1) * 20 + 1 + (q << 2)];
            dst[0] = v.x; dst[1] = v.y; dst[2] = v.z; dst[3] = v.w;
        }
        // stage weights: 32 co x 128 k (k = ci_local*16 + ky*4 + kx)
#pragma unroll
        for (int u = 0; u < 4; u++) {
            int i = t + u * 256;                    // float4 id 0..1023
            int cr = i >> 5, q = i & 31;
            float4 wv = ((const float4*)(w2 + (size_t)(cg * 32 + cr) * 2048 + c0 * 16))[q];
            *(float4*)&wl[cr * 132 + (q << 2)] = wv;
        }
        __syncthreads();
#pragma unroll 1
        for (int cl = 0; cl < 8; cl++) {
#pragma unroll 1
            for (int ky = 0; ky < 4; ky++) {
                const float* rb = &hs[cl * 360 + (2 * yo + ky) * 20];
                float r0[20];
#pragma unroll
                for (int q = 0; q < 5; q++)
                    *(float4*)&r0[q * 4] = *(const float4*)&rb[q * 4];
                float4 w4 = *(const float4*)&wl[cw * 132 + (cl << 4) + (ky << 2)];
#pragma unroll
                for (int xo = 0; xo < 8; xo++) {
                    acc[xo] = fmaf(w4.x, r0[2 * xo + 0], acc[xo]);
                    acc[xo] = fmaf(w4.y, r0[2 * xo + 1], acc[xo]);
                    acc[xo] = fmaf(w4.z, r0[2 * xo + 2], acc[xo]);
                    acc[xo] = fmaf(w4.w, r0[2 * xo + 3], acc[xo]);
                }
            }
        }
    }
    float* fb = fea + (size_t)b * 16384 + (size_t)co * 64 + yo * 8;
    float4 o0 = { fmaxf(acc[0] + bb, 0.f), fmaxf(acc[1] + bb, 0.f),
                  fmaxf(acc[2] + bb, 0.f), fmaxf(acc[3] + bb, 0.f) };
    float4 o1 = { fmaxf(acc[4] + bb, 0.f), fmaxf(acc[5] + bb, 0.f),
                  fmaxf(acc[6] + bb, 0.f), fmaxf(acc[7] + bb, 0.f) };
    *(float4*)&fb[0] = o0;
    *(float4*)&fb[4] = o1;
}

// ---------------- combined codebook: rows 0-511 = cb0, 512-1023 = cb_idx ----------------
__global__ __launch_bounds__(256) void k_comb(const float* __restrict__ cb0,
                                              const float* __restrict__ cb1,
                                              const float* __restrict__ cb2,
                                              const int* __restrict__ idxp,
                                              float* __restrict__ C) {
    int i = blockIdx.x * 256 + threadIdx.x;   // float4 id, 65536 total
    int idx = *idxp;
    const float4* lo = (const float4*)cb0;
    const float4* hi = (const float4*)((idx == 2) ? cb2 : ((idx == 1) ? cb1 : cb0));
    ((float4*)C)[i] = (i < 32768) ? lo[i] : hi[i - 32768];
}

// ---------------- half code norms (f64-exact, stored f32) ----------------
__global__ __launch_bounds__(256) void k_cnorm(const float* __restrict__ C,
                                               const int* __restrict__ idxp,
                                               float* __restrict__ cnorm) {
    int c = blockIdx.x * 256 + threadIdx.x;
    int Kc = (*idxp == 0) ? 512 : 1024;
    if (c >= 1024) return;
    if (c >= Kc) { cnorm[c] = 3.0e38f; return; }
    const float* row = C + (size_t)c * 256;
    double s = 0.0;
    for (int d = 0; d < 256; d++) { double v = row[d]; s += v * v; }
    cnorm[c] = (float)(0.5 * s);
}

// ---------------- VQ screening: top-2 per (row, wave-group) -> 8 candidates ----------------
__global__ __launch_bounds__(256) void k_vq(const float* __restrict__ fea,
                                            const float* __restrict__ C,
                                            const float* __restrict__ cnorm,
                                            const int* __restrict__ idxp,
                                            int* __restrict__ cand) {
    __shared__ float xs[16384];               // 64 KB: [d][p]
    int b = blockIdx.x, t = threadIdx.x;
    const float* fb = fea + (size_t)b * 16384;
    for (int i = t; i < 4096; i += 256)
        ((float4*)xs)[i] = ((const float4*)fb)[i];
    __syncthreads();
    int Kc = (*idxp == 0) ? 512 : 1024;
    int p = t & 63;
    int g = __builtin_amdgcn_readfirstlane(t >> 6);
    float min1 = 3.0e38f, min2 = 3.1e38f;
    int i1 = 0, i2 = 1;
    int npg = Kc >> 2;
    for (int cc = 0; cc < npg; cc += 8) {
        float s[8];
        int cidx[8];
#pragma unroll
        for (int j = 0; j < 8; j++) {
            int c = (cc + j) * 4 + g;         // wave-uniform
            cidx[j] = c;
            s[j] = cnorm[c];
        }
        for (int d0 = 0; d0 < 256; d0 += 16) {
            float xv[16];
#pragma unroll
            for (int q = 0; q < 16; q++) xv[q] = xs[(d0 + q) * 64 + p];
#pragma unroll
            for (int j = 0; j < 8; j++) {
                const float* row = C + (size_t)cidx[j] * 256 + d0;  // uniform
#pragma unroll
                for (int q = 0; q < 16; q++) s[j] = fmaf(-xv[q], row[q], s[j]);
            }
        }
#pragma unroll
        for (int j = 0; j < 8; j++) {
            float v = s[j];
            if (v < min1) { min2 = min1; i2 = i1; min1 = v; i1 = cidx[j]; }
            else if (v < min2) { min2 = v; i2 = cidx[j]; }
        }
    }
    size_t r = (size_t)b * 64 + p;
    cand[r * 8 + g * 2 + 0] = i1;
    cand[r * 8 + g * 2 + 1] = i2;
}

// ---------------- exact f64 rescore of 8 candidates; best dist IS the loss term ----------------
__global__ __launch_bounds__(256) void k_rescore(const float* __restrict__ fea,
                                                 const float* __restrict__ C,
                                                 const int* __restrict__ cand,
                                                 int* __restrict__ enc,
                                                 double* __restrict__ dloss) {
    __shared__ double dsm[256];
    __shared__ int dim_[256];
    __shared__ double bsum[32];
    int t = threadIdx.x;
    int rr = blockIdx.x * 32 + (t >> 3);      // chunk-local row
    int j = t & 7;
    int c = cand[(size_t)rr * 8 + j];
    const float* row = C + (size_t)c * 256;
    int bl = rr >> 6, p = rr & 63;
    const float* xrow = fea + (size_t)bl * 16384 + p;
    double s = 0.0;
    for (int d = 0; d < 256; d++) {
        double diff = (double)xrow[d * 64] - (double)row[d];
        s = fma(diff, diff, s);
    }
    dsm[t] = s;
    dim_[t] = c;
    __syncthreads();
    if (j == 0) {
        double best = dsm[t]; int bi = dim_[t];
        for (int q = 1; q < 8; q++) {
            double v = dsm[t + q]; int ci = dim_[t + q];
            if (v < best || (v == best && ci < bi)) { best = v; bi = ci; }
        }
        enc[rr] = bi;
        bsum[t >> 3] = best;
    }
    __syncthreads();
    if (t == 0) {
        double acc = 0.0;
        for (int q = 0; q < 32; q++) acc += bsum[q];
        atomicAdd(dloss, acc);
    }
}

// ---------------- histogram ----------------
__global__ __launch_bounds__(256) void k_hist(const int* __restrict__ enc,
                                              int* __restrict__ counts) {
    __shared__ int hc[1024];
    for (int i = threadIdx.x; i < 1024; i += 256) hc[i] = 0;
    __syncthreads();
    int base = blockIdx.x * 1024;
    for (int i = threadIdx.x; i < 1024; i += 256) atomicAdd(&hc[enc[base + i]], 1);
    __syncthreads();
    for (int i = threadIdx.x; i < 1024; i += 256)
        if (hc[i]) atomicAdd(&counts[i], hc[i]);
}

// ---------------- Wt[n][p][d] = fc1_w[n][d*64+p]  (one-time transpose) ----------------
__global__ __launch_bounds__(256) void k_wt(const float* __restrict__ W,
                                            float* __restrict__ Wt) {
    __shared__ float tile[64][65];
    int n = blockIdx.x;
    int d0 = blockIdx.y * 64;
    int t = threadIdx.x;
    const float* src = W + (size_t)n * 16384 + (size_t)d0 * 64;
#pragma unroll
    for (int u = 0; u < 4; u++) {
        int i = t + u * 256;
        float4 v = ((const float4*)src)[i];
        int dd = i >> 4;
        int p = (i & 15) << 2;
        tile[dd][p] = v.x; tile[dd][p + 1] = v.y; tile[dd][p + 2] = v.z; tile[dd][p + 3] = v.w;
    }
    __syncthreads();
    float* dst = Wt + (size_t)n * 16384 + d0;
#pragma unroll
    for (int u = 0; u < 4; u++) {
        int i = t + u * 256;
        int p = i >> 4;
        int dd = (i & 15) << 2;
        float4 v = { tile[dd][p], tile[dd + 1][p], tile[dd + 2][p], tile[dd + 3][p] };
        *(float4*)(dst + (size_t)p * 256 + dd) = v;
    }
}

// ---------------- fc1 GEMM with gathered A:  A[m][(p,d)] = C[enc[m*64+p]][d] ----------------
__global__ __launch_bounds__(256) void k_fc1g(const int* __restrict__ enc,
                                              const float* __restrict__ C,
                                              const float* __restrict__ Wt,
                                              float* __restrict__ part) {
    __shared__ float As[32][132];
    __shared__ float Bs[32][132];
    __shared__ int encs[128];
    int t = threadIdx.x;
    int m0 = blockIdx.x * 128, n0 = blockIdx.y * 128;
    int ty = t >> 4, tx = t & 15;
    float acc[8][8];
#pragma unroll
    for (int i = 0; i < 8; i++)
#pragma unroll
        for (int j = 0; j < 8; j++) acc[i][j] = 0.f;
    int p0 = blockIdx.z * 16;
    for (int p = p0; p < p0 + 16; p++) {
        __syncthreads();
        if (t < 128) encs[t] = enc[(size_t)(m0 + t) * 64 + p];
        __syncthreads();
        for (int dc = 0; dc < 256; dc += 32) {
#pragma unroll
            for (int u = 0; u < 4; u++) {
                int i = t + u * 256;
                int row = i >> 3, kq = (i & 7) << 2;
                float4 v = *(const float4*)(C + (size_t)encs[row] * 256 + dc + kq);
                As[kq + 0][row] = v.x; As[kq + 1][row] = v.y;
                As[kq + 2][row] = v.z; As[kq + 3][row] = v.w;
                float4 wv = *(const float4*)(Wt + (size_t)(n0 + row) * 16384 + p * 256 + dc + kq);
                Bs[kq + 0][row] = wv.x; Bs[kq + 1][row] = wv.y;
                Bs[kq + 2][row] = wv.z; Bs[kq + 3][row] = wv.w;
            }
            __syncthreads();
#pragma unroll
            for (int k = 0; k < 32; k++) {
                float a[8], bv[8];
                *(float4*)(a)      = *(const float4*)&As[k][ty * 8];
                *(float4*)(a + 4)  = *(const float4*)&As[k][ty * 8 + 4];
                *(float4*)(bv)     = *(const float4*)&Bs[k][tx * 8];
                *(float4*)(bv + 4) = *(const float4*)&Bs[k][tx * 8 + 4];
#pragma unroll
                for (int i = 0; i < 8; i++)
#pragma unroll
                    for (int j = 0; j < 8; j++) acc[i][j] = fmaf(a[i], bv[j], acc[i][j]);
            }
            __syncthreads();
        }
    }
    float* P = part + (size_t)blockIdx.z * (2048 * 512);
#pragma unroll
    for (int i = 0; i < 8; i++)
#pragma unroll
        for (int j = 0; j < 8; j++)
            P[(size_t)(m0 + ty * 8 + i) * 512 + (n0 + tx * 8 + j)] = acc[i][j];
}

__global__ __launch_bounds__(256) void k_fc1fin(const float* __restrict__ part,
                                                const float* __restrict__ bias,
                                                float* __restrict__ h1) {
    int i = blockIdx.x * 256 + threadIdx.x;
    float s = part[i] + part[i + 1048576] + part[i + 2097152] + part[i + 3145728];
    s += bias[i & 511];
    h1[i] = 0.5f * s * (1.f + erff(s * 0.70710678118654752f));
}

// ---------------- fc2 ----------------
__global__ __launch_bounds__(256) void k_fc2(const float* __restrict__ h1,
                                             const float* __restrict__ w,
                                             const float* __restrict__ bias,
                                             float* __restrict__ out) {
    int gid = blockIdx.x * 256 + threadIdx.x;
    if (gid >= 20480) return;
    int b = gid / 10, k = gid % 10;
    const float* hr = h1 + (size_t)b * 512;
    const float* wr = w + (size_t)k * 512;
    float acc = bias[k];
#pragma unroll 8
    for (int j = 0; j < 512; j++) acc = fmaf(hr[j], wr[j], acc);
    out[gid] = acc;
}

// ---------------- loss + perplexity ----------------
__global__ __launch_bounds__(256) void k_final(const int* __restrict__ counts,
                                               const double* __restrict__ dloss,
                                               const int* __restrict__ idxp,
                                               float* __restrict__ out) {
    __shared__ float sb[256];
    int t = threadIdx.x;
    int Kc = (*idxp == 0) ? 512 : 1024;
    float local = 0.f;
    for (int c = t; c < Kc; c += 256) {
        float pr = (float)counts[c] * (1.0f / 131072.0f);
        local += pr * logf(pr + 1e-10f);
    }
    sb[t] = local;
    __syncthreads();
    for (int o = 128; o > 0; o >>= 1) {
        if (t < o) sb[t] += sb[t + o];
        __syncthreads();
    }
    if (t == 0) {
        out[20480] = (float)(dloss[0] * 1.25 / (131072.0 * 256.0));
        out[20481] = expf(-sb[0]);
    }
}

extern "C" void kernel_launch(void* const* d_in, const int* in_sizes, int n_in,
                              void* d_out, int out_size, void* d_ws, size_t ws_size,
                              hipStream_t stream) {
    const float* x    = (const float*)d_in[0];
    const int*   idxp = (const int*)d_in[1];
    const float* w1   = (const float*)d_in[2];
    const float* b1   = (const float*)d_in[3];
    const float* w2   = (const float*)d_in[4];
    const float* b2   = (const float*)d_in[5];
    const float* cb0  = (const float*)d_in[6];
    const float* cb1  = (const float*)d_in[7];
    const float* cb2  = (const float*)d_in[8];
    const float* fc1w = (const float*)d_in[9];
    const float* fc1b = (const float*)d_in[10];
    const float* fc2w = (const float*)d_in[11];
    const float* fc2b = (const float*)d_in[12];
    float* out = (float*)d_out;

    char* ws = (char*)d_ws;
    size_t off = 0;
    float* h_c   = (float*)(ws + off); off += (size_t)CHUNK * 32768 * 4;   // 33.6 MB
    float* fea_c = (float*)(ws + off); off += (size_t)CHUNK * 16384 * 4;   // 16.8 MB
    float* Wt    = (float*)(ws + off); off += (size_t)512 * 16384 * 4;     // 33.6 MB
    float* Cc    = (float*)(ws + off); off += (size_t)1024 * 256 * 4;      //  1.0 MB
    float* part  = (float*)(ws + off); off += (size_t)4 * 2048 * 512 * 4;  // 16.8 MB
    float* h1    = (float*)(ws + off); off += (size_t)2048 * 512 * 4;      //  4.2 MB
    int*   cand  = (int*)(ws + off);   off += (size_t)CHUNK * 64 * 8 * 4;  //  0.5 MB
    int*   enc   = (int*)(ws + off);   off += (size_t)131072 * 4;          //  0.5 MB
    float* cnorm = (float*)(ws + off); off += 1024 * 4;
    int*   counts= (int*)(ws + off);   off += 1024 * 4;
    double* dloss= (double*)(ws + off); off += 8;
    // total ~107 MB

    hipMemsetAsync(counts, 0, 1024 * 4 + 8, stream);

    k_comb<<<256, 256, 0, stream>>>(cb0, cb1, cb2, idxp, Cc);
    k_cnorm<<<4, 256, 0, stream>>>(Cc, idxp, cnorm);
    k_wt<<<dim3(512, 4), 256, 0, stream>>>(fc1w, Wt);

    for (int c = 0; c < NCH; c++) {
        k_conv1<<<CHUNK, 256, 0, stream>>>(x + (size_t)c * CHUNK * 3072, w1, b1, h_c);
        k_conv2<<<dim3(CHUNK, 8), 256, 0, stream>>>(h_c, w2, b2, fea_c);
        k_vq<<<CHUNK, 256, 0, stream>>>(fea_c, Cc, cnorm, idxp, cand);
        k_rescore<<<(CHUNK * 64) / 32, 256, 0, stream>>>(fea_c, Cc, cand,
                                                         enc + (size_t)c * CHUNK * 64, dloss);
    }

    k_hist<<<128, 256, 0, stream>>>(enc, counts);
    k_fc1g<<<dim3(16, 4, 4), 256, 0, stream>>>(enc, Cc, Wt, part);
    k_fc1fin<<<4096, 256, 0, stream>>>(part, fc1b, h1);
    k_fc2<<<80, 256, 0, stream>>>(h1, fc2w, fc2b, out);
    k_final<<<1, 256, 0, stream>>>(counts, dloss, idxp, out);
}

// Round 4
// 5613.282 us; speedup vs baseline: 5.2716x; 1.8226x over previous
//
#include <hip/hip_runtime.h>
#include <hip/hip_bf16.h>
#include <math.h>

// x:(2048,3,32,32) f32; idx; w1:(128,3,4,4); b1:(128); w2:(256,128,4,4); b2:(256)
// cb0/cb1/cb2:(512,256); fc1_w:(512,16384); fc1_b:(512); fc2_w:(10,512); fc2_b:(10)
// out: 2048*10 logits ++ loss ++ perplexity = 20482 f32
// ws kept < ~110 MB.

#define CHUNK 256
#define NCH 8

// ---------------- conv1 ----------------
__global__ __launch_bounds__(256) void k_conv1(const float* __restrict__ x,
                                               const float* __restrict__ w1,
                                               const float* __restrict__ b1,
                                               float* __restrict__ h) {
    __shared__ float xs[3 * 32 * 32];
    __shared__ float w1s[128 * 48];
    __shared__ float b1s[128];
    int b = blockIdx.x, t = threadIdx.x;
    const float* xb = x + (size_t)b * 3072;
    for (int i = t; i < 768; i += 256)
        ((float4*)xs)[i] = ((const float4*)xb)[i];
    for (int i = t; i < 1536; i += 256)
        ((float4*)w1s)[i] = ((const float4*)w1)[i];
    if (t < 128) b1s[t] = b1[t];
    __syncthreads();
    int py = t >> 4, px = t & 15;
    float win[48];
#pragma unroll
    for (int ci = 0; ci < 3; ci++)
#pragma unroll
        for (int ky = 0; ky < 4; ky++) {
            int iy = 2 * py - 1 + ky;
#pragma unroll
            for (int kx = 0; kx < 4; kx++) {
                int ix = 2 * px - 1 + kx;
                bool ok = ((unsigned)iy < 32u) && ((unsigned)ix < 32u);
                win[ci * 16 + ky * 4 + kx] = ok ? xs[ci * 1024 + iy * 32 + ix] : 0.f;
            }
        }
    float* hb = h + (size_t)b * 32768;
    for (int co = 0; co < 128; co++) {
        float acc = b1s[co];
#pragma unroll
        for (int q = 0; q < 12; q++) {
            float4 w = *(const float4*)&w1s[co * 48 + q * 4];
            acc = fmaf(win[q * 4 + 0], w.x, acc);
            acc = fmaf(win[q * 4 + 1], w.y, acc);
            acc = fmaf(win[q * 4 + 2], w.z, acc);
            acc = fmaf(win[q * 4 + 3], w.w, acc);
        }
        hb[co * 256 + t] = fmaxf(acc, 0.f);
    }
}

// ---------------- conv2 (R3 version, unchanged) ----------------
__global__ __launch_bounds__(256) void k_conv2(const float* __restrict__ h,
                                               const float* __restrict__ w2,
                                               const float* __restrict__ b2,
                                               float* __restrict__ fea) {
    __shared__ float hs[8 * 18 * 20];
    __shared__ float wl[32 * 132];
    int b = blockIdx.x, cg = blockIdx.y, t = threadIdx.x;
    int l = t & 63;
    int g = __builtin_amdgcn_readfirstlane(t >> 6);
    int yo = l & 7, c8 = l >> 3;
    int cw = g * 8 + c8;
    int co = cg * 32 + cw;
    for (int i = t; i < 2880; i += 256) hs[i] = 0.f;
    float bb = b2[co];
    float acc[8];
#pragma unroll
    for (int j = 0; j < 8; j++) acc[j] = 0.f;
    const float* hb = h + (size_t)b * 32768;
    for (int c0 = 0; c0 < 128; c0 += 8) {
        __syncthreads();
#pragma unroll
        for (int u = 0; u < 2; u++) {
            int i = t + u * 256;
            int cl = i >> 6, r = (i >> 2) & 15, q = i & 3;
            float4 v = ((const float4*)(hb + (size_t)(c0 + cl) * 256))[(r << 2) + q];
            float* dst = &hs[cl * 360 + (r + 1) * 20 + 1 + (q << 2)];
            dst[0] = v.x; dst[1] = v.y; dst[2] = v.z; dst[3] = v.w;
        }
#pragma unroll
        for (int u = 0; u < 4; u++) {
            int i = t + u * 256;
            int cr = i >> 5, q = i & 31;
            float4 wv = ((const float4*)(w2 + (size_t)(cg * 32 + cr) * 2048 + c0 * 16))[q];
            *(float4*)&wl[cr * 132 + (q << 2)] = wv;
        }
        __syncthreads();
#pragma unroll 1
        for (int cl = 0; cl < 8; cl++) {
#pragma unroll 1
            for (int ky = 0; ky < 4; ky++) {
                const float* rb = &hs[cl * 360 + (2 * yo + ky) * 20];
                float r0[20];
#pragma unroll
                for (int q = 0; q < 5; q++)
                    *(float4*)&r0[q * 4] = *(const float4*)&rb[q * 4];
                float4 w4 = *(const float4*)&wl[cw * 132 + (cl << 4) + (ky << 2)];
#pragma unroll
                for (int xo = 0; xo < 8; xo++) {
                    acc[xo] = fmaf(w4.x, r0[2 * xo + 0], acc[xo]);
                    acc[xo] = fmaf(w4.y, r0[2 * xo + 1], acc[xo]);
                    acc[xo] = fmaf(w4.z, r0[2 * xo + 2], acc[xo]);
                    acc[xo] = fmaf(w4.w, r0[2 * xo + 3], acc[xo]);
                }
            }
        }
    }
    float* fb = fea + (size_t)b * 16384 + (size_t)co * 64 + yo * 8;
    float4 o0 = { fmaxf(acc[0] + bb, 0.f), fmaxf(acc[1] + bb, 0.f),
                  fmaxf(acc[2] + bb, 0.f), fmaxf(acc[3] + bb, 0.f) };
    float4 o1 = { fmaxf(acc[4] + bb, 0.f), fmaxf(acc[5] + bb, 0.f),
                  fmaxf(acc[6] + bb, 0.f), fmaxf(acc[7] + bb, 0.f) };
    *(float4*)&fb[0] = o0;
    *(float4*)&fb[4] = o1;
}

// ---------------- combined codebook ----------------
__global__ __launch_bounds__(256) void k_comb(const float* __restrict__ cb0,
                                              const float* __restrict__ cb1,
                                              const float* __restrict__ cb2,
                                              const int* __restrict__ idxp,
                                              float* __restrict__ C) {
    int i = blockIdx.x * 256 + threadIdx.x;
    int idx = *idxp;
    const float4* lo = (const float4*)cb0;
    const float4* hi = (const float4*)((idx == 2) ? cb2 : ((idx == 1) ? cb1 : cb0));
    ((float4*)C)[i] = (i < 32768) ? lo[i] : hi[i - 32768];
}

// ---------------- codebook transpose: CcT[d][n] = Cc[n][d] ----------------
__global__ __launch_bounds__(256) void k_ct(const float* __restrict__ C,
                                            float* __restrict__ Ct) {
    __shared__ float tile[64][65];
    int n0 = blockIdx.x * 64, d0 = blockIdx.y * 64, t = threadIdx.x;
#pragma unroll
    for (int u = 0; u < 4; u++) {
        int i = t + u * 256;
        int r = i >> 4, q = (i & 15) << 2;
        float4 v = *(const float4*)(C + (size_t)(n0 + r) * 256 + d0 + q);
        tile[r][q] = v.x; tile[r][q + 1] = v.y; tile[r][q + 2] = v.z; tile[r][q + 3] = v.w;
    }
    __syncthreads();
#pragma unroll
    for (int u = 0; u < 4; u++) {
        int i = t + u * 256;
        int dd = i >> 4, nq = (i & 15) << 2;
        float4 v = { tile[nq][dd], tile[nq + 1][dd], tile[nq + 2][dd], tile[nq + 3][dd] };
        *(float4*)(Ct + (size_t)(d0 + dd) * 1024 + n0 + nq) = v;
    }
}

// ---------------- half code norms ----------------
__global__ __launch_bounds__(256) void k_cnorm(const float* __restrict__ C,
                                               const int* __restrict__ idxp,
                                               float* __restrict__ cnorm) {
    int c = blockIdx.x * 256 + threadIdx.x;
    int Kc = (*idxp == 0) ? 512 : 1024;
    if (c >= 1024) return;
    if (c >= Kc) { cnorm[c] = 3.0e38f; return; }
    const float* row = C + (size_t)c * 256;
    double s = 0.0;
    for (int d = 0; d < 256; d++) { double v = row[d]; s += v * v; }
    cnorm[c] = (float)(0.5 * s);
}

// ---------------- VQ screening as tiled GEMM + fused top-2 epilogue ----------------
// grid (128, 8) per chunk: 128-pixel m-tile (2 images) x 128-code n-tile.
// score = cnorm[c] - dot(x,c); top-2 per (pixel, n-tile) -> cand[row][16].
__global__ __launch_bounds__(256) void k_vqg(const float* __restrict__ fea,
                                             const float* __restrict__ CcT,
                                             const float* __restrict__ cnorm,
                                             int* __restrict__ cand) {
    __shared__ float sbuf[8448];                     // As[32][132] ++ Bs[32][132]; reused as top2 buf
    float (*As)[132] = (float (*)[132])sbuf;
    float (*Bs)[132] = (float (*)[132])(sbuf + 4224);
    int t = threadIdx.x;
    int m0 = blockIdx.x * 128;
    int n0 = blockIdx.y * 128;
    int ty = t >> 4, tx = t & 15;
    float acc[8][8];
#pragma unroll
    for (int i = 0; i < 8; i++)
#pragma unroll
        for (int j = 0; j < 8; j++) acc[i][j] = 0.f;
    for (int k0 = 0; k0 < 256; k0 += 32) {
        __syncthreads();
#pragma unroll
        for (int u = 0; u < 4; u++) {
            int i = t + u * 256;                     // float4 id 0..1023
            int kk = i >> 5;
            int mm = (i & 31) << 2;
            int img = (m0 + mm) >> 6;
            int p = mm & 63;
            float4 v = *(const float4*)(fea + (size_t)img * 16384 + (size_t)(k0 + kk) * 64 + p);
            *(float4*)&As[kk][mm] = v;
            float4 w = *(const float4*)(CcT + (size_t)(k0 + kk) * 1024 + n0 + mm);
            *(float4*)&Bs[kk][mm] = w;
        }
        __syncthreads();
#pragma unroll
        for (int k = 0; k < 32; k++) {
            float a[8], bv[8];
            *(float4*)(a)      = *(const float4*)&As[k][ty * 8];
            *(float4*)(a + 4)  = *(const float4*)&As[k][ty * 8 + 4];
            *(float4*)(bv)     = *(const float4*)&Bs[k][tx * 8];
            *(float4*)(bv + 4) = *(const float4*)&Bs[k][tx * 8 + 4];
#pragma unroll
            for (int i = 0; i < 8; i++)
#pragma unroll
                for (int j = 0; j < 8; j++) acc[i][j] = fmaf(a[i], bv[j], acc[i][j]);
        }
    }
    __syncthreads();
    float cn[8];
#pragma unroll
    for (int j = 0; j < 8; j++) cn[j] = cnorm[n0 + tx * 8 + j];
    float* t2 = sbuf;                                // 128 px x 16 tx x 4 = 8192 floats
#pragma unroll
    for (int i = 0; i < 8; i++) {
        float v1 = 3.4e38f, v2 = 3.4e38f;
        int c1 = n0, c2 = n0;
#pragma unroll
        for (int j = 0; j < 8; j++) {
            float s = cn[j] - acc[i][j];
            int c = n0 + tx * 8 + j;
            if (s < v1) { v2 = v1; c2 = c1; v1 = s; c1 = c; }
            else if (s < v2) { v2 = s; c2 = c; }
        }
        int pp = ty * 8 + i;
        float* e = &t2[(pp * 16 + tx) * 4];
        e[0] = v1; e[1] = __int_as_float(c1); e[2] = v2; e[3] = __int_as_float(c2);
    }
    __syncthreads();
    if (t < 128) {
        float v1 = 3.4e38f, v2 = 3.4e38f;
        int c1 = 0, c2 = 0;
        for (int e = 0; e < 16; e++) {
            const float* q = &t2[(t * 16 + e) * 4];
            float a1 = q[0]; int a1c = __float_as_int(q[1]);
            float a2 = q[2]; int a2c = __float_as_int(q[3]);
            if (a1 < v1) { v2 = v1; c2 = c1; v1 = a1; c1 = a1c; }
            else if (a1 < v2) { v2 = a1; c2 = a1c; }
            if (a2 < v1) { v2 = v1; c2 = c1; v1 = a2; c1 = a2c; }
            else if (a2 < v2) { v2 = a2; c2 = a2c; }
        }
        size_t row = (size_t)m0 + t;
        cand[row * 16 + blockIdx.y * 2 + 0] = c1;
        cand[row * 16 + blockIdx.y * 2 + 1] = c2;
    }
}

// ---------------- exact f64 rescore of 16 candidates/row ----------------
__global__ __launch_bounds__(256) void k_rescore(const float* __restrict__ fea,
                                                 const float* __restrict__ C,
                                                 const int* __restrict__ cand,
                                                 int* __restrict__ enc,
                                                 double* __restrict__ dloss) {
    __shared__ double dsm[256];
    __shared__ int dim_[256];
    __shared__ double bsum[16];
    int t = threadIdx.x;
    int rr = blockIdx.x * 16 + (t >> 4);      // chunk-local row
    int j = t & 15;
    int c = cand[(size_t)rr * 16 + j];
    const float* row = C + (size_t)c * 256;
    int bl = rr >> 6, p = rr & 63;
    const float* xrow = fea + (size_t)bl * 16384 + p;
    double s = 0.0;
    for (int d = 0; d < 256; d++) {
        double diff = (double)xrow[d * 64] - (double)row[d];
        s = fma(diff, diff, s);
    }
    dsm[t] = s;
    dim_[t] = c;
    __syncthreads();
    if (j == 0) {
        double best = dsm[t]; int bi = dim_[t];
        for (int q = 1; q < 16; q++) {
            double v = dsm[t + q]; int ci = dim_[t + q];
            if (v < best || (v == best && ci < bi)) { best = v; bi = ci; }
        }
        enc[rr] = bi;
        bsum[t >> 4] = best;
    }
    __syncthreads();
    if (t == 0) {
        double acc = 0.0;
        for (int q = 0; q < 16; q++) acc += bsum[q];
        atomicAdd(dloss, acc);
    }
}

// ---------------- histogram ----------------
__global__ __launch_bounds__(256) void k_hist(const int* __restrict__ enc,
                                              int* __restrict__ counts) {
    __shared__ int hc[1024];
    for (int i = threadIdx.x; i < 1024; i += 256) hc[i] = 0;
    __syncthreads();
    int base = blockIdx.x * 1024;
    for (int i = threadIdx.x; i < 1024; i += 256) atomicAdd(&hc[enc[base + i]], 1);
    __syncthreads();
    for (int i = threadIdx.x; i < 1024; i += 256)
        if (hc[i]) atomicAdd(&counts[i], hc[i]);
}

// ---------------- Wt[n][p][d] = fc1_w[n][d*64+p] ----------------
__global__ __launch_bounds__(256) void k_wt(const float* __restrict__ W,
                                            float* __restrict__ Wt) {
    __shared__ float tile[64][65];
    int n = blockIdx.x;
    int d0 = blockIdx.y * 64;
    int t = threadIdx.x;
    const float* src = W + (size_t)n * 16384 + (size_t)d0 * 64;
#pragma unroll
    for (int u = 0; u < 4; u++) {
        int i = t + u * 256;
        float4 v = ((const float4*)src)[i];
        int dd = i >> 4;
        int p = (i & 15) << 2;
        tile[dd][p] = v.x; tile[dd][p + 1] = v.y; tile[dd][p + 2] = v.z; tile[dd][p + 3] = v.w;
    }
    __syncthreads();
    float* dst = Wt + (size_t)n * 16384 + d0;
#pragma unroll
    for (int u = 0; u < 4; u++) {
        int i = t + u * 256;
        int p = i >> 4;
        int dd = (i & 15) << 2;
        float4 v = { tile[dd][p], tile[dd + 1][p], tile[dd + 2][p], tile[dd + 3][p] };
        *(float4*)(dst + (size_t)p * 256 + dd) = v;
    }
}

// ---------------- fc1 GEMM with gathered A ----------------
__global__ __launch_bounds__(256) void k_fc1g(const int* __restrict__ enc,
                                              const float* __restrict__ C,
                                              const float* __restrict__ Wt,
                                              float* __restrict__ part) {
    __shared__ float As[32][132];
    __shared__ float Bs[32][132];
    __shared__ int encs[128];
    int t = threadIdx.x;
    int m0 = blockIdx.x * 128, n0 = blockIdx.y * 128;
    int ty = t >> 4, tx = t & 15;
    float acc[8][8];
#pragma unroll
    for (int i = 0; i < 8; i++)
#pragma unroll
        for (int j = 0; j < 8; j++) acc[i][j] = 0.f;
    int p0 = blockIdx.z * 16;
    for (int p = p0; p < p0 + 16; p++) {
        __syncthreads();
        if (t < 128) encs[t] = enc[(size_t)(m0 + t) * 64 + p];
        __syncthreads();
        for (int dc = 0; dc < 256; dc += 32) {
#pragma unroll
            for (int u = 0; u < 4; u++) {
                int i = t + u * 256;
                int row = i >> 3, kq = (i & 7) << 2;
                float4 v = *(const float4*)(C + (size_t)encs[row] * 256 + dc + kq);
                As[kq + 0][row] = v.x; As[kq + 1][row] = v.y;
                As[kq + 2][row] = v.z; As[kq + 3][row] = v.w;
                float4 wv = *(const float4*)(Wt + (size_t)(n0 + row) * 16384 + p * 256 + dc + kq);
                Bs[kq + 0][row] = wv.x; Bs[kq + 1][row] = wv.y;
                Bs[kq + 2][row] = wv.z; Bs[kq + 3][row] = wv.w;
            }
            __syncthreads();
#pragma unroll
            for (int k = 0; k < 32; k++) {
                float a[8], bv[8];
                *(float4*)(a)      = *(const float4*)&As[k][ty * 8];
                *(float4*)(a + 4)  = *(const float4*)&As[k][ty * 8 + 4];
                *(float4*)(bv)     = *(const float4*)&Bs[k][tx * 8];
                *(float4*)(bv + 4) = *(const float4*)&Bs[k][tx * 8 + 4];
#pragma unroll
                for (int i = 0; i < 8; i++)
#pragma unroll
                    for (int j = 0; j < 8; j++) acc[i][j] = fmaf(a[i], bv[j], acc[i][j]);
            }
            __syncthreads();
        }
    }
    float* P = part + (size_t)blockIdx.z * (2048 * 512);
#pragma unroll
    for (int i = 0; i < 8; i++)
#pragma unroll
        for (int j = 0; j < 8; j++)
            P[(size_t)(m0 + ty * 8 + i) * 512 + (n0 + tx * 8 + j)] = acc[i][j];
}

__global__ __launch_bounds__(256) void k_fc1fin(const float* __restrict__ part,
                                                const float* __restrict__ bias,
                                                float* __restrict__ h1) {
    int i = blockIdx.x * 256 + threadIdx.x;
    float s = part[i] + part[i + 1048576] + part[i + 2097152] + part[i + 3145728];
    s += bias[i & 511];
    h1[i] = 0.5f * s * (1.f + erff(s * 0.70710678118654752f));
}

// ---------------- fc2 ----------------
__global__ __launch_bounds__(256) void k_fc2(const float* __restrict__ h1,
                                             const float* __restrict__ w,
                                             const float* __restrict__ bias,
                                             float* __restrict__ out) {
    int gid = blockIdx.x * 256 + threadIdx.x;
    if (gid >= 20480) return;
    int b = gid / 10, k = gid % 10;
    const float* hr = h1 + (size_t)b * 512;
    const float* wr = w + (size_t)k * 512;
    float acc = bias[k];
#pragma unroll 8
    for (int j = 0; j < 512; j++) acc = fmaf(hr[j], wr[j], acc);
    out[gid] = acc;
}

// ---------------- loss + perplexity ----------------
__global__ __launch_bounds__(256) void k_final(const int* __restrict__ counts,
                                               const double* __restrict__ dloss,
                                               const int* __restrict__ idxp,
                                               float* __restrict__ out) {
    __shared__ float sb[256];
    int t = threadIdx.x;
    int Kc = (*idxp == 0) ? 512 : 1024;
    float local = 0.f;
    for (int c = t; c < Kc; c += 256) {
        float pr = (float)counts[c] * (1.0f / 131072.0f);
        local += pr * logf(pr + 1e-10f);
    }
    sb[t] = local;
    __syncthreads();
    for (int o = 128; o > 0; o >>= 1) {
        if (t < o) sb[t] += sb[t + o];
        __syncthreads();
    }
    if (t == 0) {
        out[20480] = (float)(dloss[0] * 1.25 / (131072.0 * 256.0));
        out[20481] = expf(-sb[0]);
    }
}

extern "C" void kernel_launch(void* const* d_in, const int* in_sizes, int n_in,
                              void* d_out, int out_size, void* d_ws, size_t ws_size,
                              hipStream_t stream) {
    const float* x    = (const float*)d_in[0];
    const int*   idxp = (const int*)d_in[1];
    const float* w1   = (const float*)d_in[2];
    const float* b1   = (const float*)d_in[3];
    const float* w2   = (const float*)d_in[4];
    const float* b2   = (const float*)d_in[5];
    const float* cb0  = (const float*)d_in[6];
    const float* cb1  = (const float*)d_in[7];
    const float* cb2  = (const float*)d_in[8];
    const float* fc1w = (const float*)d_in[9];
    const float* fc1b = (const float*)d_in[10];
    const float* fc2w = (const float*)d_in[11];
    const float* fc2b = (const float*)d_in[12];
    float* out = (float*)d_out;

    char* ws = (char*)d_ws;
    size_t off = 0;
    float* h_c   = (float*)(ws + off); off += (size_t)CHUNK * 32768 * 4;   // 33.6 MB
    float* fea_c = (float*)(ws + off); off += (size_t)CHUNK * 16384 * 4;   // 16.8 MB
    float* Wt    = (float*)(ws + off); off += (size_t)512 * 16384 * 4;     // 33.6 MB
    float* Cc    = (float*)(ws + off); off += (size_t)1024 * 256 * 4;      //  1.0 MB
    float* CcT   = (float*)(ws + off); off += (size_t)256 * 1024 * 4;      //  1.0 MB
    float* part  = (float*)(ws + off); off += (size_t)4 * 2048 * 512 * 4;  // 16.8 MB
    float* h1    = (float*)(ws + off); off += (size_t)2048 * 512 * 4;      //  4.2 MB
    int*   cand  = (int*)(ws + off);   off += (size_t)CHUNK * 64 * 16 * 4; //  1.0 MB
    int*   enc   = (int*)(ws + off);   off += (size_t)131072 * 4;          //  0.5 MB
    float* cnorm = (float*)(ws + off); off += 1024 * 4;
    int*   counts= (int*)(ws + off);   off += 1024 * 4;
    double* dloss= (double*)(ws + off); off += 8;
    // total ~108.6 MB

    hipMemsetAsync(counts, 0, 1024 * 4 + 8, stream);   // counts + dloss (contiguous)

    k_comb<<<256, 256, 0, stream>>>(cb0, cb1, cb2, idxp, Cc);
    k_ct<<<dim3(16, 4), 256, 0, stream>>>(Cc, CcT);
    k_cnorm<<<4, 256, 0, stream>>>(Cc, idxp, cnorm);
    k_wt<<<dim3(512, 4), 256, 0, stream>>>(fc1w, Wt);

    for (int c = 0; c < NCH; c++) {
        k_conv1<<<CHUNK, 256, 0, stream>>>(x + (size_t)c * CHUNK * 3072, w1, b1, h_c);
        k_conv2<<<dim3(CHUNK, 8), 256, 0, stream>>>(h_c, w2, b2, fea_c);
        k_vqg<<<dim3(128, 8), 256, 0, stream>>>(fea_c, CcT, cnorm, cand);
        k_rescore<<<(CHUNK * 64) / 16, 256, 0, stream>>>(fea_c, Cc, cand,
                                                         enc + (size_t)c * CHUNK * 64, dloss);
    }

    k_hist<<<128, 256, 0, stream>>>(enc, counts);
    k_fc1g<<<dim3(16, 4, 4), 256, 0, stream>>>(enc, Cc, Wt, part);
    k_fc1fin<<<4096, 256, 0, stream>>>(part, fc1b, h1);
    k_fc2<<<80, 256, 0, stream>>>(h1, fc2w, fc2b, out);
    k_final<<<1, 256, 0, stream>>>(counts, dloss, idxp, out);
}

// Round 5
// 4304.096 us; speedup vs baseline: 6.8750x; 1.3042x over previous
//
#include <hip/hip_runtime.h>
#include <hip/hip_bf16.h>
#include <math.h>

// x:(2048,3,32,32) f32; idx; w1:(128,3,4,4); b1:(128); w2:(256,128,4,4); b2:(256)
// cb0/cb1/cb2:(512,256); fc1_w:(512,16384); fc1_b:(512); fc2_w:(10,512); fc2_b:(10)
// out: 2048*10 logits ++ loss ++ perplexity = 20482 f32

#define CHUNK 256
#define NCH 8

// ---------------- conv1 ----------------
__global__ __launch_bounds__(256) void k_conv1(const float* __restrict__ x,
                                               const float* __restrict__ w1,
                                               const float* __restrict__ b1,
                                               float* __restrict__ h) {
    __shared__ float xs[3 * 32 * 32];
    __shared__ float w1s[128 * 48];
    __shared__ float b1s[128];
    int b = blockIdx.x, t = threadIdx.x;
    const float* xb = x + (size_t)b * 3072;
    for (int i = t; i < 768; i += 256)
        ((float4*)xs)[i] = ((const float4*)xb)[i];
    for (int i = t; i < 1536; i += 256)
        ((float4*)w1s)[i] = ((const float4*)w1)[i];
    if (t < 128) b1s[t] = b1[t];
    __syncthreads();
    int py = t >> 4, px = t & 15;
    float win[48];
#pragma unroll
    for (int ci = 0; ci < 3; ci++)
#pragma unroll
        for (int ky = 0; ky < 4; ky++) {
            int iy = 2 * py - 1 + ky;
#pragma unroll
            for (int kx = 0; kx < 4; kx++) {
                int ix = 2 * px - 1 + kx;
                bool ok = ((unsigned)iy < 32u) && ((unsigned)ix < 32u);
                win[ci * 16 + ky * 4 + kx] = ok ? xs[ci * 1024 + iy * 32 + ix] : 0.f;
            }
        }
    float* hb = h + (size_t)b * 32768;
    for (int co = 0; co < 128; co++) {
        float acc = b1s[co];
#pragma unroll
        for (int q = 0; q < 12; q++) {
            float4 w = *(const float4*)&w1s[co * 48 + q * 4];
            acc = fmaf(win[q * 4 + 0], w.x, acc);
            acc = fmaf(win[q * 4 + 1], w.y, acc);
            acc = fmaf(win[q * 4 + 2], w.z, acc);
            acc = fmaf(win[q * 4 + 3], w.w, acc);
        }
        hb[co * 256 + t] = fmaxf(acc, 0.f);
    }
}

// ---------------- conv2 v3: 2-half co split, 4co x 8xo per thread, VALU-bound ----------------
// grid (CHUNK, 2). Block: image b, co half (128 co). Thread: yo = l&7, c8 = l>>3,
// wave g; computes co_loc = g*32 + j*8 + c8 (j=0..3) x 8 xo.
// Per (cl,ky): 5 b128 row reads (2-way free) + 4 b128 weight reads (all-32-bank) vs 128 FMA.
__global__ __launch_bounds__(256, 2) void k_conv2(const float* __restrict__ h,
                                                  const float* __restrict__ w2,
                                                  const float* __restrict__ b2,
                                                  float* __restrict__ fea) {
    __shared__ float hs[8 * 18 * 20];   // 11.5 KB, borders zero
    __shared__ float wl[128 * 132];     // 67.6 KB
    int b = blockIdx.x, half = blockIdx.y, t = threadIdx.x;
    int l = t & 63;
    int g = __builtin_amdgcn_readfirstlane(t >> 6);
    int yo = l & 7, c8 = l >> 3;
    for (int i = t; i < 2880; i += 256) hs[i] = 0.f;
    float acc[4][8];
#pragma unroll
    for (int j = 0; j < 4; j++)
#pragma unroll
        for (int xo = 0; xo < 8; xo++) acc[j][xo] = 0.f;
    const float* hb = h + (size_t)b * 32768;
    const float* wbase = w2 + (size_t)half * 128 * 2048;
    for (int c0 = 0; c0 < 128; c0 += 8) {
        __syncthreads();
#pragma unroll
        for (int u = 0; u < 2; u++) {
            int i = t + u * 256;
            int cl = i >> 6, r = (i >> 2) & 15, q = i & 3;
            float4 v = ((const float4*)(hb + (size_t)(c0 + cl) * 256))[(r << 2) + q];
            float* dst = &hs[cl * 360 + (r + 1) * 20 + 1 + (q << 2)];
            dst[0] = v.x; dst[1] = v.y; dst[2] = v.z; dst[3] = v.w;
        }
#pragma unroll
        for (int u = 0; u < 16; u++) {
            int i = t + u * 256;                 // float4 id 0..4095
            int cr = i >> 5, q = i & 31;
            float4 wv = ((const float4*)(wbase + (size_t)cr * 2048 + c0 * 16))[q];
            *(float4*)&wl[cr * 132 + (q << 2)] = wv;
        }
        __syncthreads();
#pragma unroll 1
        for (int cl = 0; cl < 8; cl++) {
#pragma unroll 1
            for (int ky = 0; ky < 4; ky++) {
                const float* rb = &hs[cl * 360 + (2 * yo + ky) * 20];
                float r0[20];
#pragma unroll
                for (int q = 0; q < 5; q++)
                    *(float4*)&r0[q * 4] = *(const float4*)&rb[q * 4];
#pragma unroll
                for (int j = 0; j < 4; j++) {
                    float4 w4 = *(const float4*)&wl[(g * 32 + j * 8 + c8) * 132 + (cl << 4) + (ky << 2)];
#pragma unroll
                    for (int xo = 0; xo < 8; xo++) {
                        acc[j][xo] = fmaf(w4.x, r0[2 * xo + 0], acc[j][xo]);
                        acc[j][xo] = fmaf(w4.y, r0[2 * xo + 1], acc[j][xo]);
                        acc[j][xo] = fmaf(w4.z, r0[2 * xo + 2], acc[j][xo]);
                        acc[j][xo] = fmaf(w4.w, r0[2 * xo + 3], acc[j][xo]);
                    }
                }
            }
        }
    }
#pragma unroll
    for (int j = 0; j < 4; j++) {
        int co = half * 128 + g * 32 + j * 8 + c8;
        float bb = b2[co];
        float* fb = fea + (size_t)b * 16384 + (size_t)co * 64 + yo * 8;
        float4 o0 = { fmaxf(acc[j][0] + bb, 0.f), fmaxf(acc[j][1] + bb, 0.f),
                      fmaxf(acc[j][2] + bb, 0.f), fmaxf(acc[j][3] + bb, 0.f) };
        float4 o1 = { fmaxf(acc[j][4] + bb, 0.f), fmaxf(acc[j][5] + bb, 0.f),
                      fmaxf(acc[j][6] + bb, 0.f), fmaxf(acc[j][7] + bb, 0.f) };
        *(float4*)&fb[0] = o0;
        *(float4*)&fb[4] = o1;
    }
}

// ---------------- combined codebook ----------------
__global__ __launch_bounds__(256) void k_comb(const float* __restrict__ cb0,
                                              const float* __restrict__ cb1,
                                              const float* __restrict__ cb2,
                                              const int* __restrict__ idxp,
                                              float* __restrict__ C) {
    int i = blockIdx.x * 256 + threadIdx.x;
    int idx = *idxp;
    const float4* lo = (const float4*)cb0;
    const float4* hi = (const float4*)((idx == 2) ? cb2 : ((idx == 1) ? cb1 : cb0));
    ((float4*)C)[i] = (i < 32768) ? lo[i] : hi[i - 32768];
}

// ---------------- codebook transpose ----------------
__global__ __launch_bounds__(256) void k_ct(const float* __restrict__ C,
                                            float* __restrict__ Ct) {
    __shared__ float tile[64][65];
    int n0 = blockIdx.x * 64, d0 = blockIdx.y * 64, t = threadIdx.x;
#pragma unroll
    for (int u = 0; u < 4; u++) {
        int i = t + u * 256;
        int r = i >> 4, q = (i & 15) << 2;
        float4 v = *(const float4*)(C + (size_t)(n0 + r) * 256 + d0 + q);
        tile[r][q] = v.x; tile[r][q + 1] = v.y; tile[r][q + 2] = v.z; tile[r][q + 3] = v.w;
    }
    __syncthreads();
#pragma unroll
    for (int u = 0; u < 4; u++) {
        int i = t + u * 256;
        int dd = i >> 4, nq = (i & 15) << 2;
        float4 v = { tile[nq][dd], tile[nq + 1][dd], tile[nq + 2][dd], tile[nq + 3][dd] };
        *(float4*)(Ct + (size_t)(d0 + dd) * 1024 + n0 + nq) = v;
    }
}

// ---------------- half code norms ----------------
__global__ __launch_bounds__(256) void k_cnorm(const float* __restrict__ C,
                                               const int* __restrict__ idxp,
                                               float* __restrict__ cnorm) {
    int c = blockIdx.x * 256 + threadIdx.x;
    int Kc = (*idxp == 0) ? 512 : 1024;
    if (c >= 1024) return;
    if (c >= Kc) { cnorm[c] = 3.0e38f; return; }
    const float* row = C + (size_t)c * 256;
    double s = 0.0;
    for (int d = 0; d < 256; d++) { double v = row[d]; s += v * v; }
    cnorm[c] = (float)(0.5 * s);
}

// ---------------- VQ screening GEMM + fused top-2 epilogue ----------------
__global__ __launch_bounds__(256) void k_vqg(const float* __restrict__ fea,
                                             const float* __restrict__ CcT,
                                             const float* __restrict__ cnorm,
                                             int* __restrict__ cand) {
    __shared__ float sbuf[8448];
    float (*As)[132] = (float (*)[132])sbuf;
    float (*Bs)[132] = (float (*)[132])(sbuf + 4224);
    int t = threadIdx.x;
    int m0 = blockIdx.x * 128;
    int n0 = blockIdx.y * 128;
    int ty = t >> 4, tx = t & 15;
    float acc[8][8];
#pragma unroll
    for (int i = 0; i < 8; i++)
#pragma unroll
        for (int j = 0; j < 8; j++) acc[i][j] = 0.f;
    for (int k0 = 0; k0 < 256; k0 += 32) {
        __syncthreads();
#pragma unroll
        for (int u = 0; u < 4; u++) {
            int i = t + u * 256;
            int kk = i >> 5;
            int mm = (i & 31) << 2;
            int img = (m0 + mm) >> 6;
            int p = mm & 63;
            float4 v = *(const float4*)(fea + (size_t)img * 16384 + (size_t)(k0 + kk) * 64 + p);
            *(float4*)&As[kk][mm] = v;
            float4 w = *(const float4*)(CcT + (size_t)(k0 + kk) * 1024 + n0 + mm);
            *(float4*)&Bs[kk][mm] = w;
        }
        __syncthreads();
#pragma unroll
        for (int k = 0; k < 32; k++) {
            float a[8], bv[8];
            *(float4*)(a)      = *(const float4*)&As[k][ty * 8];
            *(float4*)(a + 4)  = *(const float4*)&As[k][ty * 8 + 4];
            *(float4*)(bv)     = *(const float4*)&Bs[k][tx * 8];
            *(float4*)(bv + 4) = *(const float4*)&Bs[k][tx * 8 + 4];
#pragma unroll
            for (int i = 0; i < 8; i++)
#pragma unroll
                for (int j = 0; j < 8; j++) acc[i][j] = fmaf(a[i], bv[j], acc[i][j]);
        }
    }
    __syncthreads();
    float cn[8];
#pragma unroll
    for (int j = 0; j < 8; j++) cn[j] = cnorm[n0 + tx * 8 + j];
    float* t2 = sbuf;
#pragma unroll
    for (int i = 0; i < 8; i++) {
        float v1 = 3.4e38f, v2 = 3.4e38f;
        int c1 = n0, c2 = n0;
#pragma unroll
        for (int j = 0; j < 8; j++) {
            float s = cn[j] - acc[i][j];
            int c = n0 + tx * 8 + j;
            if (s < v1) { v2 = v1; c2 = c1; v1 = s; c1 = c; }
            else if (s < v2) { v2 = s; c2 = c; }
        }
        int pp = ty * 8 + i;
        float* e = &t2[(pp * 16 + tx) * 4];
        e[0] = v1; e[1] = __int_as_float(c1); e[2] = v2; e[3] = __int_as_float(c2);
    }
    __syncthreads();
    if (t < 128) {
        float v1 = 3.4e38f, v2 = 3.4e38f;
        int c1 = 0, c2 = 0;
        for (int e = 0; e < 16; e++) {
            const float* q = &t2[(t * 16 + e) * 4];
            float a1 = q[0]; int a1c = __float_as_int(q[1]);
            float a2 = q[2]; int a2c = __float_as_int(q[3]);
            if (a1 < v1) { v2 = v1; c2 = c1; v1 = a1; c1 = a1c; }
            else if (a1 < v2) { v2 = a1; c2 = a1c; }
            if (a2 < v1) { v2 = v1; c2 = c1; v1 = a2; c1 = a2c; }
            else if (a2 < v2) { v2 = a2; c2 = a2c; }
        }
        size_t row = (size_t)m0 + t;
        cand[row * 16 + blockIdx.y * 2 + 0] = c1;
        cand[row * 16 + blockIdx.y * 2 + 1] = c2;
    }
}

// ---------------- exact f64 rescore of 16 candidates/row ----------------
__global__ __launch_bounds__(256) void k_rescore(const float* __restrict__ fea,
                                                 const float* __restrict__ C,
                                                 const int* __restrict__ cand,
                                                 int* __restrict__ enc,
                                                 double* __restrict__ dloss) {
    __shared__ double dsm[256];
    __shared__ int dim_[256];
    __shared__ double bsum[16];
    int t = threadIdx.x;
    int rr = blockIdx.x * 16 + (t >> 4);
    int j = t & 15;
    int c = cand[(size_t)rr * 16 + j];
    const float* row = C + (size_t)c * 256;
    int bl = rr >> 6, p = rr & 63;
    const float* xrow = fea + (size_t)bl * 16384 + p;
    double s = 0.0;
    for (int d = 0; d < 256; d++) {
        double diff = (double)xrow[d * 64] - (double)row[d];
        s = fma(diff, diff, s);
    }
    dsm[t] = s;
    dim_[t] = c;
    __syncthreads();
    if (j == 0) {
        double best = dsm[t]; int bi = dim_[t];
        for (int q = 1; q < 16; q++) {
            double v = dsm[t + q]; int ci = dim_[t + q];
            if (v < best || (v == best && ci < bi)) { best = v; bi = ci; }
        }
        enc[rr] = bi;
        bsum[t >> 4] = best;
    }
    __syncthreads();
    if (t == 0) {
        double acc = 0.0;
        for (int q = 0; q < 16; q++) acc += bsum[q];
        atomicAdd(dloss, acc);
    }
}

// ---------------- histogram ----------------
__global__ __launch_bounds__(256) void k_hist(const int* __restrict__ enc,
                                              int* __restrict__ counts) {
    __shared__ int hc[1024];
    for (int i = threadIdx.x; i < 1024; i += 256) hc[i] = 0;
    __syncthreads();
    int base = blockIdx.x * 1024;
    for (int i = threadIdx.x; i < 1024; i += 256) atomicAdd(&hc[enc[base + i]], 1);
    __syncthreads();
    for (int i = threadIdx.x; i < 1024; i += 256)
        if (hc[i]) atomicAdd(&counts[i], hc[i]);
}

// ---------------- Wt[n][p][d] = fc1_w[n][d*64+p] ----------------
__global__ __launch_bounds__(256) void k_wt(const float* __restrict__ W,
                                            float* __restrict__ Wt) {
    __shared__ float tile[64][65];
    int n = blockIdx.x;
    int d0 = blockIdx.y * 64;
    int t = threadIdx.x;
    const float* src = W + (size_t)n * 16384 + (size_t)d0 * 64;
#pragma unroll
    for (int u = 0; u < 4; u++) {
        int i = t + u * 256;
        float4 v = ((const float4*)src)[i];
        int dd = i >> 4;
        int p = (i & 15) << 2;
        tile[dd][p] = v.x; tile[dd][p + 1] = v.y; tile[dd][p + 2] = v.z; tile[dd][p + 3] = v.w;
    }
    __syncthreads();
    float* dst = Wt + (size_t)n * 16384 + d0;
#pragma unroll
    for (int u = 0; u < 4; u++) {
        int i = t + u * 256;
        int p = i >> 4;
        int dd = (i & 15) << 2;
        float4 v = { tile[dd][p], tile[dd + 1][p], tile[dd + 2][p], tile[dd + 3][p] };
        *(float4*)(dst + (size_t)p * 256 + dd) = v;
    }
}

// ---------------- fc1 GEMM with gathered A, split-K z=8 ----------------
__global__ __launch_bounds__(256) void k_fc1g(const int* __restrict__ enc,
                                              const float* __restrict__ C,
                                              const float* __restrict__ Wt,
                                              float* __restrict__ part) {
    __shared__ float As[32][132];
    __shared__ float Bs[32][132];
    __shared__ int encs[128];
    int t = threadIdx.x;
    int m0 = blockIdx.x * 128, n0 = blockIdx.y * 128;
    int ty = t >> 4, tx = t & 15;
    float acc[8][8];
#pragma unroll
    for (int i = 0; i < 8; i++)
#pragma unroll
        for (int j = 0; j < 8; j++) acc[i][j] = 0.f;
    int p0 = blockIdx.z * 8;
    for (int p = p0; p < p0 + 8; p++) {
        __syncthreads();
        if (t < 128) encs[t] = enc[(size_t)(m0 + t) * 64 + p];
        __syncthreads();
        for (int dc = 0; dc < 256; dc += 32) {
#pragma unroll
            for (int u = 0; u < 4; u++) {
                int i = t + u * 256;
                int row = i >> 3, kq = (i & 7) << 2;
                float4 v = *(const float4*)(C + (size_t)encs[row] * 256 + dc + kq);
                As[kq + 0][row] = v.x; As[kq + 1][row] = v.y;
                As[kq + 2][row] = v.z; As[kq + 3][row] = v.w;
                float4 wv = *(const float4*)(Wt + (size_t)(n0 + row) * 16384 + p * 256 + dc + kq);
                Bs[kq + 0][row] = wv.x; Bs[kq + 1][row] = wv.y;
                Bs[kq + 2][row] = wv.z; Bs[kq + 3][row] = wv.w;
            }
            __syncthreads();
#pragma unroll
            for (int k = 0; k < 32; k++) {
                float a[8], bv[8];
                *(float4*)(a)      = *(const float4*)&As[k][ty * 8];
                *(float4*)(a + 4)  = *(const float4*)&As[k][ty * 8 + 4];
                *(float4*)(bv)     = *(const float4*)&Bs[k][tx * 8];
                *(float4*)(bv + 4) = *(const float4*)&Bs[k][tx * 8 + 4];
#pragma unroll
                for (int i = 0; i < 8; i++)
#pragma unroll
                    for (int j = 0; j < 8; j++) acc[i][j] = fmaf(a[i], bv[j], acc[i][j]);
            }
            __syncthreads();
        }
    }
    float* P = part + (size_t)blockIdx.z * (2048 * 512);
#pragma unroll
    for (int i = 0; i < 8; i++)
#pragma unroll
        for (int j = 0; j < 8; j++)
            P[(size_t)(m0 + ty * 8 + i) * 512 + (n0 + tx * 8 + j)] = acc[i][j];
}

__global__ __launch_bounds__(256) void k_fc1fin(const float* __restrict__ part,
                                                const float* __restrict__ bias,
                                                float* __restrict__ h1) {
    int i = blockIdx.x * 256 + threadIdx.x;
    float s = 0.f;
#pragma unroll
    for (int z = 0; z < 8; z++) s += part[i + (size_t)z * 1048576];
    s += bias[i & 511];
    h1[i] = 0.5f * s * (1.f + erff(s * 0.70710678118654752f));
}

// ---------------- fc2 ----------------
__global__ __launch_bounds__(256) void k_fc2(const float* __restrict__ h1,
                                             const float* __restrict__ w,
                                             const float* __restrict__ bias,
                                             float* __restrict__ out) {
    int gid = blockIdx.x * 256 + threadIdx.x;
    if (gid >= 20480) return;
    int b = gid / 10, k = gid % 10;
    const float* hr = h1 + (size_t)b * 512;
    const float* wr = w + (size_t)k * 512;
    float acc = bias[k];
#pragma unroll 8
    for (int j = 0; j < 512; j++) acc = fmaf(hr[j], wr[j], acc);
    out[gid] = acc;
}

// ---------------- loss + perplexity ----------------
__global__ __launch_bounds__(256) void k_final(const int* __restrict__ counts,
                                               const double* __restrict__ dloss,
                                               const int* __restrict__ idxp,
                                               float* __restrict__ out) {
    __shared__ float sb[256];
    int t = threadIdx.x;
    int Kc = (*idxp == 0) ? 512 : 1024;
    float local = 0.f;
    for (int c = t; c < Kc; c += 256) {
        float pr = (float)counts[c] * (1.0f / 131072.0f);
        local += pr * logf(pr + 1e-10f);
    }
    sb[t] = local;
    __syncthreads();
    for (int o = 128; o > 0; o >>= 1) {
        if (t < o) sb[t] += sb[t + o];
        __syncthreads();
    }
    if (t == 0) {
        out[20480] = (float)(dloss[0] * 1.25 / (131072.0 * 256.0));
        out[20481] = expf(-sb[0]);
    }
}

extern "C" void kernel_launch(void* const* d_in, const int* in_sizes, int n_in,
                              void* d_out, int out_size, void* d_ws, size_t ws_size,
                              hipStream_t stream) {
    const float* x    = (const float*)d_in[0];
    const int*   idxp = (const int*)d_in[1];
    const float* w1   = (const float*)d_in[2];
    const float* b1   = (const float*)d_in[3];
    const float* w2   = (const float*)d_in[4];
    const float* b2   = (const float*)d_in[5];
    const float* cb0  = (const float*)d_in[6];
    const float* cb1  = (const float*)d_in[7];
    const float* cb2  = (const float*)d_in[8];
    const float* fc1w = (const float*)d_in[9];
    const float* fc1b = (const float*)d_in[10];
    const float* fc2w = (const float*)d_in[11];
    const float* fc2b = (const float*)d_in[12];
    float* out = (float*)d_out;

    char* ws = (char*)d_ws;
    size_t off = 0;
    float* h_c   = (float*)(ws + off); off += (size_t)CHUNK * 32768 * 4;   // 33.6 MB (aliased by part)
    float* fea_c = (float*)(ws + off); off += (size_t)CHUNK * 16384 * 4;   // 16.8 MB
    float* Wt    = (float*)(ws + off); off += (size_t)512 * 16384 * 4;     // 33.6 MB
    float* Cc    = (float*)(ws + off); off += (size_t)1024 * 256 * 4;      //  1.0 MB
    float* CcT   = (float*)(ws + off); off += (size_t)256 * 1024 * 4;      //  1.0 MB
    float* h1    = (float*)(ws + off); off += (size_t)2048 * 512 * 4;      //  4.2 MB
    int*   cand  = (int*)(ws + off);   off += (size_t)CHUNK * 64 * 16 * 4; //  1.0 MB
    int*   enc   = (int*)(ws + off);   off += (size_t)131072 * 4;          //  0.5 MB
    float* cnorm = (float*)(ws + off); off += 1024 * 4;
    int*   counts= (int*)(ws + off);   off += 1024 * 4;
    double* dloss= (double*)(ws + off); off += 8;
    // total ~92 MB; part (8*2048*512*4 = 32 MB) aliases h_c (dead after chunk loop)
    float* part  = h_c;

    hipMemsetAsync(counts, 0, 1024 * 4 + 8, stream);   // counts + dloss (contiguous)

    k_comb<<<256, 256, 0, stream>>>(cb0, cb1, cb2, idxp, Cc);
    k_ct<<<dim3(16, 4), 256, 0, stream>>>(Cc, CcT);
    k_cnorm<<<4, 256, 0, stream>>>(Cc, idxp, cnorm);
    k_wt<<<dim3(512, 4), 256, 0, stream>>>(fc1w, Wt);

    for (int c = 0; c < NCH; c++) {
        k_conv1<<<CHUNK, 256, 0, stream>>>(x + (size_t)c * CHUNK * 3072, w1, b1, h_c);
        k_conv2<<<dim3(CHUNK, 2), 256, 0, stream>>>(h_c, w2, b2, fea_c);
        k_vqg<<<dim3(128, 8), 256, 0, stream>>>(fea_c, CcT, cnorm, cand);
        k_rescore<<<(CHUNK * 64) / 16, 256, 0, stream>>>(fea_c, Cc, cand,
                                                         enc + (size_t)c * CHUNK * 64, dloss);
    }

    k_hist<<<128, 256, 0, stream>>>(enc, counts);
    k_fc1g<<<dim3(16, 4, 8), 256, 0, stream>>>(enc, Cc, Wt, part);
    k_fc1fin<<<4096, 256, 0, stream>>>(part, fc1b, h1);
    k_fc2<<<80, 256, 0, stream>>>(h1, fc2w, fc2b, out);
    k_final<<<1, 256, 0, stream>>>(counts, dloss, idxp, out);
}

// Round 6
// 3850.068 us; speedup vs baseline: 7.6858x; 1.1179x over previous
//
#include <hip/hip_runtime.h>
#include <hip/hip_bf16.h>
#include <math.h>

// x:(2048,3,32,32) f32; idx; w1:(128,3,4,4); b1:(128); w2:(256,128,4,4); b2:(256)
// cb0/cb1/cb2:(512,256); fc1_w:(512,16384); fc1_b:(512); fc2_w:(10,512); fc2_b:(10)
// out: 2048*10 logits ++ loss ++ perplexity = 20482 f32
// Precision plan: conv1/conv2 exact fp32 (feeds argmin); VQ screening + fc1/fc2 in
// bf16 MFMA (screening protected by exact f64 rescore of 16 candidates/row).

#define CHUNK 256
#define NCH 8

typedef __attribute__((ext_vector_type(8))) short short8;   // 8 bf16 = 4 VGPR
typedef __attribute__((ext_vector_type(4))) float f32x4;

__device__ inline unsigned short f2bf(float v) {
    __hip_bfloat16 h = __float2bfloat16(v);   // RNE
    return *reinterpret_cast<unsigned short*>(&h);
}

// ---------------- conv1: weights via wave-uniform global (s_load), x via LDS ----------------
__global__ __launch_bounds__(256) void k_conv1(const float* __restrict__ x,
                                               const float* __restrict__ w1,
                                               const float* __restrict__ b1,
                                               float* __restrict__ h) {
    __shared__ float xs[3 * 32 * 32];
    int b = blockIdx.x, t = threadIdx.x;
    const float* xb = x + (size_t)b * 3072;
    for (int i = t; i < 768; i += 256)
        ((float4*)xs)[i] = ((const float4*)xb)[i];
    __syncthreads();
    int py = t >> 4, px = t & 15;
    float win[48];
#pragma unroll
    for (int ci = 0; ci < 3; ci++)
#pragma unroll
        for (int ky = 0; ky < 4; ky++) {
            int iy = 2 * py - 1 + ky;
#pragma unroll
            for (int kx = 0; kx < 4; kx++) {
                int ix = 2 * px - 1 + kx;
                bool ok = ((unsigned)iy < 32u) && ((unsigned)ix < 32u);
                win[ci * 16 + ky * 4 + kx] = ok ? xs[ci * 1024 + iy * 32 + ix] : 0.f;
            }
        }
    float* hb = h + (size_t)b * 32768;
    for (int co = 0; co < 128; co++) {
        const float* w = w1 + co * 48;    // uniform -> scalar K$ loads
        float acc = b1[co];
#pragma unroll
        for (int q = 0; q < 48; q++) acc = fmaf(win[q], w[q], acc);
        hb[co * 256 + t] = fmaxf(acc, 0.f);
    }
}

// ---------------- conv2 (fp32, R5 structure) + bf16 fea side-store ----------------
__global__ __launch_bounds__(256, 2) void k_conv2(const float* __restrict__ h,
                                                  const float* __restrict__ w2,
                                                  const float* __restrict__ b2,
                                                  float* __restrict__ fea,
                                                  unsigned short* __restrict__ fea_bf) {
    __shared__ float hs[8 * 18 * 20];
    __shared__ float wl[128 * 132];
    int b = blockIdx.x, half = blockIdx.y, t = threadIdx.x;
    int l = t & 63;
    int g = __builtin_amdgcn_readfirstlane(t >> 6);
    int yo = l & 7, c8 = l >> 3;
    for (int i = t; i < 2880; i += 256) hs[i] = 0.f;
    float acc[4][8];
#pragma unroll
    for (int j = 0; j < 4; j++)
#pragma unroll
        for (int xo = 0; xo < 8; xo++) acc[j][xo] = 0.f;
    const float* hb = h + (size_t)b * 32768;
    const float* wbase = w2 + (size_t)half * 128 * 2048;
    for (int c0 = 0; c0 < 128; c0 += 8) {
        __syncthreads();
#pragma unroll
        for (int u = 0; u < 2; u++) {
            int i = t + u * 256;
            int cl = i >> 6, r = (i >> 2) & 15, q = i & 3;
            float4 v = ((const float4*)(hb + (size_t)(c0 + cl) * 256))[(r << 2) + q];
            float* dst = &hs[cl * 360 + (r + 1) * 20 + 1 + (q << 2)];
            dst[0] = v.x; dst[1] = v.y; dst[2] = v.z; dst[3] = v.w;
        }
#pragma unroll
        for (int u = 0; u < 16; u++) {
            int i = t + u * 256;
            int cr = i >> 5, q = i & 31;
            float4 wv = ((const float4*)(wbase + (size_t)cr * 2048 + c0 * 16))[q];
            *(float4*)&wl[cr * 132 + (q << 2)] = wv;
        }
        __syncthreads();
#pragma unroll 1
        for (int cl = 0; cl < 8; cl++) {
#pragma unroll 1
            for (int ky = 0; ky < 4; ky++) {
                const float* rb = &hs[cl * 360 + (2 * yo + ky) * 20];
                float r0[20];
#pragma unroll
                for (int q = 0; q < 5; q++)
                    *(float4*)&r0[q * 4] = *(const float4*)&rb[q * 4];
#pragma unroll
                for (int j = 0; j < 4; j++) {
                    float4 w4 = *(const float4*)&wl[(g * 32 + j * 8 + c8) * 132 + (cl << 4) + (ky << 2)];
#pragma unroll
                    for (int xo = 0; xo < 8; xo++) {
                        acc[j][xo] = fmaf(w4.x, r0[2 * xo + 0], acc[j][xo]);
                        acc[j][xo] = fmaf(w4.y, r0[2 * xo + 1], acc[j][xo]);
                        acc[j][xo] = fmaf(w4.z, r0[2 * xo + 2], acc[j][xo]);
                        acc[j][xo] = fmaf(w4.w, r0[2 * xo + 3], acc[j][xo]);
                    }
                }
            }
        }
    }
#pragma unroll
    for (int j = 0; j < 4; j++) {
        int co = half * 128 + g * 32 + j * 8 + c8;
        float bb = b2[co];
        float o[8];
#pragma unroll
        for (int xo = 0; xo < 8; xo++) o[xo] = fmaxf(acc[j][xo] + bb, 0.f);
        float* fb = fea + (size_t)b * 16384 + (size_t)co * 64 + yo * 8;
        *(float4*)&fb[0] = *(float4*)&o[0];
        *(float4*)&fb[4] = *(float4*)&o[4];
        unsigned short* fq = fea_bf + (size_t)b * 16384 + co;
#pragma unroll
        for (int xo = 0; xo < 8; xo++)
            fq[(size_t)(yo * 8 + xo) * 256] = f2bf(o[xo]);
    }
}

// ---------------- combined codebook (f32 + bf16) ----------------
__global__ __launch_bounds__(256) void k_comb(const float* __restrict__ cb0,
                                              const float* __restrict__ cb1,
                                              const float* __restrict__ cb2,
                                              const int* __restrict__ idxp,
                                              float* __restrict__ C,
                                              unsigned short* __restrict__ Cbf) {
    int i = blockIdx.x * 256 + threadIdx.x;   // float4 id, 65536 total
    int idx = *idxp;
    const float4* lo = (const float4*)cb0;
    const float4* hi = (const float4*)((idx == 2) ? cb2 : ((idx == 1) ? cb1 : cb0));
    float4 v = (i < 32768) ? lo[i] : hi[i - 32768];
    ((float4*)C)[i] = v;
    ushort4 u = { f2bf(v.x), f2bf(v.y), f2bf(v.z), f2bf(v.w) };
    *(ushort4*)(Cbf + (size_t)i * 4) = u;
}

// ---------------- half code norms ----------------
__global__ __launch_bounds__(256) void k_cnorm(const float* __restrict__ C,
                                               const int* __restrict__ idxp,
                                               float* __restrict__ cnorm) {
    int c = blockIdx.x * 256 + threadIdx.x;
    int Kc = (*idxp == 0) ? 512 : 1024;
    if (c >= 1024) return;
    if (c >= Kc) { cnorm[c] = 3.0e38f; return; }
    const float* row = C + (size_t)c * 256;
    double s = 0.0;
    for (int d = 0; d < 256; d++) { double v = row[d]; s += v * v; }
    cnorm[c] = (float)(0.5 * s);
}

// ---------------- VQ screening: bf16 MFMA GEMM + fused top-2/128-codes ----------------
// grid (128, 8): 128-row m-tile x 128-code n-tile, K=256. m97 pattern: 4 waves,
// each 4x4 frags of 16x16x32. Screening noise ~0.05 is harmless: exact f64 rescore
// picks the argmin among 16 candidates.
__global__ __launch_bounds__(256) void k_vqg(const unsigned short* __restrict__ fea_bf,
                                             const unsigned short* __restrict__ Cbf,
                                             const float* __restrict__ cnorm,
                                             int* __restrict__ cand) {
    __shared__ char smem[18944];
    unsigned short* As = (unsigned short*)smem;            // 8 KB [m][32k]
    unsigned short* Bs = (unsigned short*)(smem + 8192);   // 8 KB [n][32k]
    float* t2 = (float*)smem;                              // 16 KB (reused post-K)
    float* t3 = (float*)(smem + 16384);                    // 2 KB
    int t = threadIdx.x;
    int m0 = blockIdx.x * 128, n0 = blockIdx.y * 128;
    int L = t & 63, w = t >> 6;
    int quad = L >> 4, lc = L & 15;
    int mw = (w >> 1) * 64, nw = (w & 1) * 64;
    f32x4 acc[4][4];
#pragma unroll
    for (int i = 0; i < 4; i++)
#pragma unroll
        for (int j = 0; j < 4; j++) acc[i][j] = (f32x4){0.f, 0.f, 0.f, 0.f};
    for (int k0 = 0; k0 < 256; k0 += 32) {
        __syncthreads();
#pragma unroll
        for (int u = 0; u < 2; u++) {
            int idx = t + u * 256;                 // 0..511
            int m = idx >> 2, kq = idx & 3;
            int gm = m0 + m;
            const unsigned short* ga = fea_bf + ((size_t)(gm >> 6) * 64 + (gm & 63)) * 256 + k0 + kq * 8;
            *(uint4*)(As + m * 32 + kq * 8) = *(const uint4*)ga;
            const unsigned short* gb = Cbf + (size_t)(n0 + m) * 256 + k0 + kq * 8;
            *(uint4*)(Bs + m * 32 + kq * 8) = *(const uint4*)gb;
        }
        __syncthreads();
        short8 a[4], bv[4];
#pragma unroll
        for (int i = 0; i < 4; i++)
            a[i] = *(const short8*)(As + (mw + i * 16 + lc) * 32 + quad * 8);
#pragma unroll
        for (int j = 0; j < 4; j++)
            bv[j] = *(const short8*)(Bs + (nw + j * 16 + lc) * 32 + quad * 8);
#pragma unroll
        for (int i = 0; i < 4; i++)
#pragma unroll
            for (int j = 0; j < 4; j++)
                acc[i][j] = __builtin_amdgcn_mfma_f32_16x16x32_bf16(a[i], bv[j], acc[i][j], 0, 0, 0);
    }
    float cn[4];
#pragma unroll
    for (int j = 0; j < 4; j++) cn[j] = cnorm[n0 + nw + j * 16 + lc];
    __syncthreads();
    // 4 passes of 32 rows: write raw scores -> two-stage top-2 merge
    for (int P = 0; P < 4; P++) {
        if ((w >> 1) == (P >> 1)) {
#pragma unroll
            for (int mi = 0; mi < 2; mi++) {
                int mt = (P & 1) * 2 + mi;
#pragma unroll
                for (int reg = 0; reg < 4; reg++) {
                    int rp = mi * 16 + quad * 4 + reg;     // 0..31
#pragma unroll
                    for (int j = 0; j < 4; j++)
                        t2[rp * 128 + nw + j * 16 + lc] = cn[j] - acc[mt][j][reg];
                }
            }
        }
        __syncthreads();
        if (t < 128) {
            int row = t >> 2, q = t & 3;
            const float* sr = &t2[row * 128 + q * 32];
            float v1 = 3.4e38f, v2 = 3.4e38f; int c1 = 0, c2 = 0;
            for (int e = 0; e < 32; e++) {
                float s = sr[e]; int c = q * 32 + e;
                if (s < v1) { v2 = v1; c2 = c1; v1 = s; c1 = c; }
                else if (s < v2) { v2 = s; c2 = c; }
            }
            float* e3 = &t3[(row * 4 + q) * 4];
            e3[0] = v1; e3[1] = __int_as_float(c1); e3[2] = v2; e3[3] = __int_as_float(c2);
        }
        __syncthreads();
        if (t < 32) {
            float v1 = 3.4e38f, v2 = 3.4e38f; int c1 = 0, c2 = 0;
            for (int q = 0; q < 4; q++) {
                const float* e3 = &t3[(t * 4 + q) * 4];
                float a1 = e3[0]; int a1c = __float_as_int(e3[1]);
                float a2 = e3[2]; int a2c = __float_as_int(e3[3]);
                if (a1 < v1) { v2 = v1; c2 = c1; v1 = a1; c1 = a1c; }
                else if (a1 < v2) { v2 = a1; c2 = a1c; }
                if (a2 < v1) { v2 = v1; c2 = c1; v1 = a2; c1 = a2c; }
                else if (a2 < v2) { v2 = a2; c2 = a2c; }
            }
            size_t row = (size_t)m0 + P * 32 + t;
            cand[row * 16 + blockIdx.y * 2 + 0] = n0 + c1;
            cand[row * 16 + blockIdx.y * 2 + 1] = n0 + c2;
        }
        __syncthreads();
    }
}

// ---------------- exact f64 rescore of 16 candidates/row (loss = sum best) ----------------
__global__ __launch_bounds__(256) void k_rescore(const float* __restrict__ fea,
                                                 const float* __restrict__ C,
                                                 const int* __restrict__ cand,
                                                 int* __restrict__ enc,
                                                 double* __restrict__ dloss) {
    __shared__ double dsm[256];
    __shared__ int dim_[256];
    __shared__ double bsum[16];
    int t = threadIdx.x;
    int rr = blockIdx.x * 16 + (t >> 4);
    int j = t & 15;
    int c = cand[(size_t)rr * 16 + j];
    const float* row = C + (size_t)c * 256;
    int bl = rr >> 6, p = rr & 63;
    const float* xrow = fea + (size_t)bl * 16384 + p;
    double s = 0.0;
    for (int d = 0; d < 256; d++) {
        double diff = (double)xrow[d * 64] - (double)row[d];
        s = fma(diff, diff, s);
    }
    dsm[t] = s;
    dim_[t] = c;
    __syncthreads();
    if (j == 0) {
        double best = dsm[t]; int bi = dim_[t];
        for (int q = 1; q < 16; q++) {
            double v = dsm[t + q]; int ci = dim_[t + q];
            if (v < best || (v == best && ci < bi)) { best = v; bi = ci; }
        }
        enc[rr] = bi;
        bsum[t >> 4] = best;
    }
    __syncthreads();
    if (t == 0) {
        double acc = 0.0;
        for (int q = 0; q < 16; q++) acc += bsum[q];
        atomicAdd(dloss, acc);
    }
}

// ---------------- histogram ----------------
__global__ __launch_bounds__(256) void k_hist(const int* __restrict__ enc,
                                              int* __restrict__ counts) {
    __shared__ int hc[1024];
    for (int i = threadIdx.x; i < 1024; i += 256) hc[i] = 0;
    __syncthreads();
    int base = blockIdx.x * 1024;
    for (int i = threadIdx.x; i < 1024; i += 256) atomicAdd(&hc[enc[base + i]], 1);
    __syncthreads();
    for (int i = threadIdx.x; i < 1024; i += 256)
        if (hc[i]) atomicAdd(&counts[i], hc[i]);
}

// ---------------- Wt_bf[n][p][d] = bf16(fc1_w[n][d*64+p]) ----------------
__global__ __launch_bounds__(256) void k_wt(const float* __restrict__ W,
                                            unsigned short* __restrict__ Wt) {
    __shared__ float tile[64][65];
    int n = blockIdx.x;
    int d0 = blockIdx.y * 64;
    int t = threadIdx.x;
    const float* src = W + (size_t)n * 16384 + (size_t)d0 * 64;
#pragma unroll
    for (int u = 0; u < 4; u++) {
        int i = t + u * 256;
        float4 v = ((const float4*)src)[i];
        int dd = i >> 4;
        int p = (i & 15) << 2;
        tile[dd][p] = v.x; tile[dd][p + 1] = v.y; tile[dd][p + 2] = v.z; tile[dd][p + 3] = v.w;
    }
    __syncthreads();
    unsigned short* dst = Wt + (size_t)n * 16384 + d0;
#pragma unroll
    for (int u = 0; u < 4; u++) {
        int i = t + u * 256;
        int p = i >> 4;
        int dd = (i & 15) << 2;
        ushort4 v = { f2bf(tile[dd][p]), f2bf(tile[dd + 1][p]),
                      f2bf(tile[dd + 2][p]), f2bf(tile[dd + 3][p]) };
        *(ushort4*)(dst + (size_t)p * 256 + dd) = v;
    }
}

// ---------------- fc1 bf16 MFMA GEMM with gathered A, split-K z=8 ----------------
// A[m][k=p*256+d] = Cbf[enc[m*64+p]][d];  B = Wt_bf[n][k].  m97 pattern.
__global__ __launch_bounds__(256) void k_fc1g(const int* __restrict__ enc,
                                              const unsigned short* __restrict__ Cbf,
                                              const unsigned short* __restrict__ Wt,
                                              float* __restrict__ part) {
    __shared__ unsigned short As[128 * 32];
    __shared__ unsigned short Bs[128 * 32];
    __shared__ int encs[128];
    int t = threadIdx.x;
    int m0 = blockIdx.x * 128, n0 = blockIdx.y * 128;
    int L = t & 63, w = t >> 6;
    int quad = L >> 4, lc = L & 15;
    int mw = (w >> 1) * 64, nw = (w & 1) * 64;
    f32x4 acc[4][4];
#pragma unroll
    for (int i = 0; i < 4; i++)
#pragma unroll
        for (int j = 0; j < 4; j++) acc[i][j] = (f32x4){0.f, 0.f, 0.f, 0.f};
    int p0 = blockIdx.z * 8;
    for (int p = p0; p < p0 + 8; p++) {
        __syncthreads();
        if (t < 128) encs[t] = enc[(size_t)(m0 + t) * 64 + p];
        __syncthreads();
        for (int dseg = 0; dseg < 256; dseg += 32) {
#pragma unroll
            for (int u = 0; u < 2; u++) {
                int idx = t + u * 256;
                int m = idx >> 2, kq = idx & 3;
                const unsigned short* ga = Cbf + (size_t)encs[m] * 256 + dseg + kq * 8;
                *(uint4*)(As + m * 32 + kq * 8) = *(const uint4*)ga;
                const unsigned short* gb = Wt + (size_t)(n0 + m) * 16384 + p * 256 + dseg + kq * 8;
                *(uint4*)(Bs + m * 32 + kq * 8) = *(const uint4*)gb;
            }
            __syncthreads();
            short8 a[4], bv[4];
#pragma unroll
            for (int i = 0; i < 4; i++)
                a[i] = *(const short8*)(As + (mw + i * 16 + lc) * 32 + quad * 8);
#pragma unroll
            for (int j = 0; j < 4; j++)
                bv[j] = *(const short8*)(Bs + (nw + j * 16 + lc) * 32 + quad * 8);
#pragma unroll
            for (int i = 0; i < 4; i++)
#pragma unroll
                for (int j = 0; j < 4; j++)
                    acc[i][j] = __builtin_amdgcn_mfma_f32_16x16x32_bf16(a[i], bv[j], acc[i][j], 0, 0, 0);
            __syncthreads();
        }
    }
    float* P = part + (size_t)blockIdx.z * (2048 * 512);
#pragma unroll
    for (int i = 0; i < 4; i++)
#pragma unroll
        for (int j = 0; j < 4; j++)
#pragma unroll
            for (int reg = 0; reg < 4; reg++) {
                int row = m0 + mw + i * 16 + quad * 4 + reg;
                int col = n0 + nw + j * 16 + lc;
                P[(size_t)row * 512 + col] = acc[i][j][reg];
            }
}

__global__ __launch_bounds__(256) void k_fc1fin(const float* __restrict__ part,
                                                const float* __restrict__ bias,
                                                float* __restrict__ h1) {
    int i = blockIdx.x * 256 + threadIdx.x;
    float s = 0.f;
#pragma unroll
    for (int z = 0; z < 8; z++) s += part[i + (size_t)z * 1048576];
    s += bias[i & 511];
    h1[i] = 0.5f * s * (1.f + erff(s * 0.70710678118654752f));
}

// ---------------- fc2 ----------------
__global__ __launch_bounds__(256) void k_fc2(const float* __restrict__ h1,
                                             const float* __restrict__ w,
                                             const float* __restrict__ bias,
                                             float* __restrict__ out) {
    int gid = blockIdx.x * 256 + threadIdx.x;
    if (gid >= 20480) return;
    int b = gid / 10, k = gid % 10;
    const float* hr = h1 + (size_t)b * 512;
    const float* wr = w + (size_t)k * 512;
    float acc = bias[k];
#pragma unroll 8
    for (int j = 0; j < 512; j++) acc = fmaf(hr[j], wr[j], acc);
    out[gid] = acc;
}

// ---------------- loss + perplexity ----------------
__global__ __launch_bounds__(256) void k_final(const int* __restrict__ counts,
                                               const double* __restrict__ dloss,
                                               const int* __restrict__ idxp,
                                               float* __restrict__ out) {
    __shared__ float sb[256];
    int t = threadIdx.x;
    int Kc = (*idxp == 0) ? 512 : 1024;
    float local = 0.f;
    for (int c = t; c < Kc; c += 256) {
        float pr = (float)counts[c] * (1.0f / 131072.0f);
        local += pr * logf(pr + 1e-10f);
    }
    sb[t] = local;
    __syncthreads();
    for (int o = 128; o > 0; o >>= 1) {
        if (t < o) sb[t] += sb[t + o];
        __syncthreads();
    }
    if (t == 0) {
        out[20480] = (float)(dloss[0] * 1.25 / (131072.0 * 256.0));
        out[20481] = expf(-sb[0]);
    }
}

extern "C" void kernel_launch(void* const* d_in, const int* in_sizes, int n_in,
                              void* d_out, int out_size, void* d_ws, size_t ws_size,
                              hipStream_t stream) {
    const float* x    = (const float*)d_in[0];
    const int*   idxp = (const int*)d_in[1];
    const float* w1   = (const float*)d_in[2];
    const float* b1   = (const float*)d_in[3];
    const float* w2   = (const float*)d_in[4];
    const float* b2   = (const float*)d_in[5];
    const float* cb0  = (const float*)d_in[6];
    const float* cb1  = (const float*)d_in[7];
    const float* cb2  = (const float*)d_in[8];
    const float* fc1w = (const float*)d_in[9];
    const float* fc1b = (const float*)d_in[10];
    const float* fc2w = (const float*)d_in[11];
    const float* fc2b = (const float*)d_in[12];
    float* out = (float*)d_out;

    char* ws = (char*)d_ws;
    size_t off = 0;
    float*          h_c    = (float*)(ws + off);          off += (size_t)CHUNK * 32768 * 4;   // 33.6 MB (part aliases)
    float*          fea_c  = (float*)(ws + off);          off += (size_t)CHUNK * 16384 * 4;   // 16.8 MB
    unsigned short* fea_bf = (unsigned short*)(ws + off); off += (size_t)CHUNK * 16384 * 2;   //  8.4 MB
    unsigned short* Wt_bf  = (unsigned short*)(ws + off); off += (size_t)512 * 16384 * 2;     // 16.8 MB
    float*          Cc     = (float*)(ws + off);          off += (size_t)1024 * 256 * 4;      //  1.0 MB
    unsigned short* Cc_bf  = (unsigned short*)(ws + off); off += (size_t)1024 * 256 * 2;      //  0.5 MB
    float*          h1     = (float*)(ws + off);          off += (size_t)2048 * 512 * 4;      //  4.2 MB
    int*            cand   = (int*)(ws + off);            off += (size_t)CHUNK * 64 * 16 * 4; //  1.0 MB
    int*            enc    = (int*)(ws + off);            off += (size_t)131072 * 4;          //  0.5 MB
    float*          cnorm  = (float*)(ws + off);          off += 1024 * 4;
    int*            counts = (int*)(ws + off);            off += 1024 * 4;
    double*         dloss  = (double*)(ws + off);         off += 8;
    // total ~83 MB; part (8*2048*512*4 = 33.55 MB) aliases h_c (dead after chunk loop)
    float* part = h_c;

    hipMemsetAsync(counts, 0, 1024 * 4 + 8, stream);   // counts + dloss (contiguous)

    k_comb<<<256, 256, 0, stream>>>(cb0, cb1, cb2, idxp, Cc, Cc_bf);
    k_cnorm<<<4, 256, 0, stream>>>(Cc, idxp, cnorm);
    k_wt<<<dim3(512, 4), 256, 0, stream>>>(fc1w, Wt_bf);

    for (int c = 0; c < NCH; c++) {
        k_conv1<<<CHUNK, 256, 0, stream>>>(x + (size_t)c * CHUNK * 3072, w1, b1, h_c);
        k_conv2<<<dim3(CHUNK, 2), 256, 0, stream>>>(h_c, w2, b2, fea_c, fea_bf);
        k_vqg<<<dim3(128, 8), 256, 0, stream>>>(fea_bf, Cc_bf, cnorm, cand);
        k_rescore<<<(CHUNK * 64) / 16, 256, 0, stream>>>(fea_c, Cc, cand,
                                                         enc + (size_t)c * CHUNK * 64, dloss);
    }

    k_hist<<<128, 256, 0, stream>>>(enc, counts);
    k_fc1g<<<dim3(16, 4, 8), 256, 0, stream>>>(enc, Cc_bf, Wt_bf, part);
    k_fc1fin<<<4096, 256, 0, stream>>>(part, fc1b, h1);
    k_fc2<<<80, 256, 0, stream>>>(h1, fc2w, fc2b, out);
    k_final<<<1, 256, 0, stream>>>(counts, dloss, idxp, out);
}

// Round 7
// 2039.264 us; speedup vs baseline: 14.5105x; 1.8880x over previous
//
#include <hip/hip_runtime.h>
#include <hip/hip_bf16.h>
#include <hip/hip_fp16.h>
#include <math.h>

// x:(2048,3,32,32) f32; idx; w1:(128,3,4,4); b1:(128); w2:(256,128,4,4); b2:(256)
// cb0/cb1/cb2:(512,256); fc1_w:(512,16384); fc1_b:(512); fc2_w:(10,512); fc2_b:(10)
// out: 2048*10 logits ++ loss ++ perplexity = 20482 f32
// Precision plan: conv1 fp32; conv2 split-f16 MFMA (hi + lo*2^-11 pairs, 4 products,
// scale-separated accumulators -> fp32-class fea, no denormal f16 los). VQ screening
// bf16 MFMA + exact f64 rescore of 16 candidates. fc1 bf16 MFMA. fc2 fp32.

#define CHUNK 256
#define NCH 8

typedef __attribute__((ext_vector_type(8))) short short8;            // 8 bf16
typedef __attribute__((ext_vector_type(8))) _Float16 half8;          // 8 f16
typedef __attribute__((ext_vector_type(8))) unsigned short ushort8v;
typedef __attribute__((ext_vector_type(4))) float f32x4;

__device__ inline unsigned short f2bf(float v) {
    __hip_bfloat16 h = __float2bfloat16(v);   // RNE
    return *reinterpret_cast<unsigned short*>(&h);
}

// ---------------- conv1: fp32, emits split-f16 h (hi + lo*2^-11), layout [b][px][ci] ----------------
__global__ __launch_bounds__(256) void k_conv1(const float* __restrict__ x,
                                               const float* __restrict__ w1,
                                               const float* __restrict__ b1,
                                               unsigned short* __restrict__ h_hi,
                                               unsigned short* __restrict__ h_lo) {
    __shared__ float xs[3 * 32 * 32];
    int b = blockIdx.x, t = threadIdx.x;
    const float* xb = x + (size_t)b * 3072;
    for (int i = t; i < 768; i += 256)
        ((float4*)xs)[i] = ((const float4*)xb)[i];
    __syncthreads();
    int py = t >> 4, px = t & 15;
    float win[48];
#pragma unroll
    for (int ci = 0; ci < 3; ci++)
#pragma unroll
        for (int ky = 0; ky < 4; ky++) {
            int iy = 2 * py - 1 + ky;
#pragma unroll
            for (int kx = 0; kx < 4; kx++) {
                int ix = 2 * px - 1 + kx;
                bool ok = ((unsigned)iy < 32u) && ((unsigned)ix < 32u);
                win[ci * 16 + ky * 4 + kx] = ok ? xs[ci * 1024 + iy * 32 + ix] : 0.f;
            }
        }
    unsigned short* dh = h_hi + ((size_t)b * 256 + t) * 128;
    unsigned short* dl = h_lo + ((size_t)b * 256 + t) * 128;
    for (int cg = 0; cg < 16; cg++) {
        ushort8v hi8, lo8;
#pragma unroll
        for (int j = 0; j < 8; j++) {
            int co = cg * 8 + j;
            const float* w = w1 + co * 48;    // wave-uniform -> scalar K$ loads
            float acc = b1[co];
#pragma unroll
            for (int q = 0; q < 48; q++) acc = fmaf(win[q], w[q], acc);
            float v = fmaxf(acc, 0.f);
            __half hh = __float2half(v);
            float hf = __half2float(hh);
            __half ll = __float2half((v - hf) * 2048.0f);   // lo scaled 2^11: stays normal-range
            hi8[j] = __half_as_ushort(hh);
            lo8[j] = __half_as_ushort(ll);
        }
        *(ushort8v*)(dh + cg * 8) = hi8;
        *(ushort8v*)(dl + cg * 8) = lo8;
    }
}

// ---------------- w2 prep: [co][ci][tap] -> split-f16 [co][tap][ci] ----------------
__global__ __launch_bounds__(256) void k_w2p(const float* __restrict__ w2,
                                             unsigned short* __restrict__ Wh,
                                             unsigned short* __restrict__ Wl) {
    int co = blockIdx.x, t = threadIdx.x;
#pragma unroll
    for (int k = 0; k < 8; k++) {
        int e = t + k * 256;                  // 0..2047
        int ci = e >> 4, tap = e & 15;
        float v = w2[(size_t)co * 2048 + e];
        __half hh = __float2half(v);
        __half ll = __float2half((v - __half2float(hh)) * 2048.0f);
        Wh[(size_t)co * 2048 + tap * 128 + ci] = __half_as_ushort(hh);
        Wl[(size_t)co * 2048 + tap * 128 + ci] = __half_as_ushort(ll);
    }
}

// ---------------- conv2 as split-f16 MFMA im2col GEMM ----------------
// grid (CHUNK, 2): block = (image, 128-co half). M=64 out-px, N=128 co, K=16 taps x 128 ci.
// 4 products into 3 scale-separated accs: hh + (h_hi*w_lo + h_lo*w_hi)*2^-11 + h_lo*w_lo*2^-22.
// LDS rows padded to 40 shorts (80 B): frag reads are clean 2-way (free).
__global__ __launch_bounds__(256, 2) void k_conv2m(const unsigned short* __restrict__ h_hi,
                                                   const unsigned short* __restrict__ h_lo,
                                                   const unsigned short* __restrict__ Wh,
                                                   const unsigned short* __restrict__ Wl,
                                                   const float* __restrict__ b2,
                                                   float* __restrict__ fea,
                                                   unsigned short* __restrict__ fea_bf) {
    __shared__ unsigned short Ah[64 * 40], Al[64 * 40], Bh[128 * 40], Bl[128 * 40];  // 30 KB
    int img = blockIdx.x, nh = blockIdx.y, t = threadIdx.x;
    int L = t & 63, w = t >> 6;
    int quad = L >> 4, lc = L & 15;
    int mw = (w >> 1) * 32, nw = (w & 1) * 64;
    int am = t >> 2, as = t & 3;              // A staging: row (out-px), 8-ci segment
    int ayo = am >> 3, axo = am & 7;
    int bn = t >> 1, bp = t & 1;              // B staging: row (co), half
    f32x4 a0[2][4], a1[2][4], a2[2][4];
#pragma unroll
    for (int i = 0; i < 2; i++)
#pragma unroll
        for (int j = 0; j < 4; j++) {
            a0[i][j] = (f32x4){0.f, 0.f, 0.f, 0.f};
            a1[i][j] = (f32x4){0.f, 0.f, 0.f, 0.f};
            a2[i][j] = (f32x4){0.f, 0.f, 0.f, 0.f};
        }
    for (int tap = 0; tap < 16; tap++) {
        int ky = tap >> 2, kx = tap & 3;
        int iy = 2 * ayo - 1 + ky, ix = 2 * axo - 1 + kx;
        bool valid = ((unsigned)iy < 16u) && ((unsigned)ix < 16u);
        long aoff = ((long)img * 256 + iy * 16 + ix) * 128;   // only deref if valid
        const unsigned short* wh = Wh + ((size_t)(nh * 128 + bn)) * 2048 + tap * 128;
        const unsigned short* wl = Wl + ((size_t)(nh * 128 + bn)) * 2048 + tap * 128;
        for (int c4 = 0; c4 < 4; c4++) {
            int ci0 = c4 * 32;
            __syncthreads();
            uint4 vh = {0, 0, 0, 0}, vl = {0, 0, 0, 0};
            if (valid) {
                vh = *(const uint4*)(h_hi + aoff + ci0 + as * 8);
                vl = *(const uint4*)(h_lo + aoff + ci0 + as * 8);
            }
            *(uint4*)(Ah + am * 40 + as * 8) = vh;
            *(uint4*)(Al + am * 40 + as * 8) = vl;
#pragma unroll
            for (int u = 0; u < 2; u++) {
                int s = bp * 2 + u;
                *(uint4*)(Bh + bn * 40 + s * 8) = *(const uint4*)(wh + ci0 + s * 8);
                *(uint4*)(Bl + bn * 40 + s * 8) = *(const uint4*)(wl + ci0 + s * 8);
            }
            __syncthreads();
            half8 ah[2], al_[2], bh[4], bl[4];
#pragma unroll
            for (int i = 0; i < 2; i++) {
                ah[i]  = *(const half8*)(Ah + (mw + i * 16 + lc) * 40 + quad * 8);
                al_[i] = *(const half8*)(Al + (mw + i * 16 + lc) * 40 + quad * 8);
            }
#pragma unroll
            for (int j = 0; j < 4; j++) {
                bh[j] = *(const half8*)(Bh + (nw + j * 16 + lc) * 40 + quad * 8);
                bl[j] = *(const half8*)(Bl + (nw + j * 16 + lc) * 40 + quad * 8);
            }
#pragma unroll
            for (int i = 0; i < 2; i++)
#pragma unroll
                for (int j = 0; j < 4; j++) {
                    a0[i][j] = __builtin_amdgcn_mfma_f32_16x16x32_f16(ah[i],  bh[j], a0[i][j], 0, 0, 0);
                    a1[i][j] = __builtin_amdgcn_mfma_f32_16x16x32_f16(ah[i],  bl[j], a1[i][j], 0, 0, 0);
                    a1[i][j] = __builtin_amdgcn_mfma_f32_16x16x32_f16(al_[i], bh[j], a1[i][j], 0, 0, 0);
                    a2[i][j] = __builtin_amdgcn_mfma_f32_16x16x32_f16(al_[i], bl[j], a2[i][j], 0, 0, 0);
                }
        }
    }
    const float c1 = 4.8828125e-4f;           // 2^-11
    const float c2 = 2.384185791015625e-7f;   // 2^-22
    float bb[4];
#pragma unroll
    for (int j = 0; j < 4; j++) bb[j] = b2[nh * 128 + nw + j * 16 + lc];
#pragma unroll
    for (int i = 0; i < 2; i++)
#pragma unroll
        for (int j = 0; j < 4; j++)
#pragma unroll
            for (int reg = 0; reg < 4; reg++) {
                int px = mw + i * 16 + quad * 4 + reg;
                int co = nh * 128 + nw + j * 16 + lc;
                float v = a0[i][j][reg] + c1 * a1[i][j][reg] + c2 * a2[i][j][reg] + bb[j];
                v = fmaxf(v, 0.f);
                fea[(size_t)img * 16384 + (size_t)co * 64 + px] = v;
                fea_bf[((size_t)img * 64 + px) * 256 + co] = f2bf(v);
            }
}

// ---------------- combined codebook (f32 + bf16) ----------------
__global__ __launch_bounds__(256) void k_comb(const float* __restrict__ cb0,
                                              const float* __restrict__ cb1,
                                              const float* __restrict__ cb2,
                                              const int* __restrict__ idxp,
                                              float* __restrict__ C,
                                              unsigned short* __restrict__ Cbf) {
    int i = blockIdx.x * 256 + threadIdx.x;
    int idx = *idxp;
    const float4* lo = (const float4*)cb0;
    const float4* hi = (const float4*)((idx == 2) ? cb2 : ((idx == 1) ? cb1 : cb0));
    float4 v = (i < 32768) ? lo[i] : hi[i - 32768];
    ((float4*)C)[i] = v;
    ushort4 u = { f2bf(v.x), f2bf(v.y), f2bf(v.z), f2bf(v.w) };
    *(ushort4*)(Cbf + (size_t)i * 4) = u;
}

// ---------------- half code norms ----------------
__global__ __launch_bounds__(256) void k_cnorm(const float* __restrict__ C,
                                               const int* __restrict__ idxp,
                                               float* __restrict__ cnorm) {
    int c = blockIdx.x * 256 + threadIdx.x;
    int Kc = (*idxp == 0) ? 512 : 1024;
    if (c >= 1024) return;
    if (c >= Kc) { cnorm[c] = 3.0e38f; return; }
    const float* row = C + (size_t)c * 256;
    double s = 0.0;
    for (int d = 0; d < 256; d++) { double v = row[d]; s += v * v; }
    cnorm[c] = (float)(0.5 * s);
}

// ---------------- VQ screening: bf16 MFMA GEMM + fused top-2/128-codes ----------------
__global__ __launch_bounds__(256) void k_vqg(const unsigned short* __restrict__ fea_bf,
                                             const unsigned short* __restrict__ Cbf,
                                             const float* __restrict__ cnorm,
                                             int* __restrict__ cand) {
    __shared__ char smem[18944];
    unsigned short* As = (unsigned short*)smem;
    unsigned short* Bs = (unsigned short*)(smem + 8192);
    float* t2 = (float*)smem;
    float* t3 = (float*)(smem + 16384);
    int t = threadIdx.x;
    int m0 = blockIdx.x * 128, n0 = blockIdx.y * 128;
    int L = t & 63, w = t >> 6;
    int quad = L >> 4, lc = L & 15;
    int mw = (w >> 1) * 64, nw = (w & 1) * 64;
    f32x4 acc[4][4];
#pragma unroll
    for (int i = 0; i < 4; i++)
#pragma unroll
        for (int j = 0; j < 4; j++) acc[i][j] = (f32x4){0.f, 0.f, 0.f, 0.f};
    for (int k0 = 0; k0 < 256; k0 += 32) {
        __syncthreads();
#pragma unroll
        for (int u = 0; u < 2; u++) {
            int idx = t + u * 256;
            int m = idx >> 2, kq = idx & 3;
            int gm = m0 + m;
            const unsigned short* ga = fea_bf + ((size_t)(gm >> 6) * 64 + (gm & 63)) * 256 + k0 + kq * 8;
            *(uint4*)(As + m * 32 + kq * 8) = *(const uint4*)ga;
            const unsigned short* gb = Cbf + (size_t)(n0 + m) * 256 + k0 + kq * 8;
            *(uint4*)(Bs + m * 32 + kq * 8) = *(const uint4*)gb;
        }
        __syncthreads();
        short8 a[4], bv[4];
#pragma unroll
        for (int i = 0; i < 4; i++)
            a[i] = *(const short8*)(As + (mw + i * 16 + lc) * 32 + quad * 8);
#pragma unroll
        for (int j = 0; j < 4; j++)
            bv[j] = *(const short8*)(Bs + (nw + j * 16 + lc) * 32 + quad * 8);
#pragma unroll
        for (int i = 0; i < 4; i++)
#pragma unroll
            for (int j = 0; j < 4; j++)
                acc[i][j] = __builtin_amdgcn_mfma_f32_16x16x32_bf16(a[i], bv[j], acc[i][j], 0, 0, 0);
    }
    float cn[4];
#pragma unroll
    for (int j = 0; j < 4; j++) cn[j] = cnorm[n0 + nw + j * 16 + lc];
    __syncthreads();
    for (int P = 0; P < 4; P++) {
        if ((w >> 1) == (P >> 1)) {
#pragma unroll
            for (int mi = 0; mi < 2; mi++) {
                int mt = (P & 1) * 2 + mi;
#pragma unroll
                for (int reg = 0; reg < 4; reg++) {
                    int rp = mi * 16 + quad * 4 + reg;
#pragma unroll
                    for (int j = 0; j < 4; j++)
                        t2[rp * 128 + nw + j * 16 + lc] = cn[j] - acc[mt][j][reg];
                }
            }
        }
        __syncthreads();
        if (t < 128) {
            int row = t >> 2, q = t & 3;
            const float* sr = &t2[row * 128 + q * 32];
            float v1 = 3.4e38f, v2 = 3.4e38f; int c1 = 0, c2 = 0;
            for (int e = 0; e < 32; e++) {
                float s = sr[e]; int c = q * 32 + e;
                if (s < v1) { v2 = v1; c2 = c1; v1 = s; c1 = c; }
                else if (s < v2) { v2 = s; c2 = c; }
            }
            float* e3 = &t3[(row * 4 + q) * 4];
            e3[0] = v1; e3[1] = __int_as_float(c1); e3[2] = v2; e3[3] = __int_as_float(c2);
        }
        __syncthreads();
        if (t < 32) {
            float v1 = 3.4e38f, v2 = 3.4e38f; int c1 = 0, c2 = 0;
            for (int q = 0; q < 4; q++) {
                const float* e3 = &t3[(t * 4 + q) * 4];
                float a1 = e3[0]; int a1c = __float_as_int(e3[1]);
                float a2 = e3[2]; int a2c = __float_as_int(e3[3]);
                if (a1 < v1) { v2 = v1; c2 = c1; v1 = a1; c1 = a1c; }
                else if (a1 < v2) { v2 = a1; c2 = a1c; }
                if (a2 < v1) { v2 = v1; c2 = c1; v1 = a2; c1 = a2c; }
                else if (a2 < v2) { v2 = a2; c2 = a2c; }
            }
            size_t row = (size_t)m0 + P * 32 + t;
            cand[row * 16 + blockIdx.y * 2 + 0] = n0 + c1;
            cand[row * 16 + blockIdx.y * 2 + 1] = n0 + c2;
        }
        __syncthreads();
    }
}

// ---------------- exact f64 rescore of 16 candidates/row ----------------
__global__ __launch_bounds__(256) void k_rescore(const float* __restrict__ fea,
                                                 const float* __restrict__ C,
                                                 const int* __restrict__ cand,
                                                 int* __restrict__ enc,
                                                 double* __restrict__ dloss) {
    __shared__ double dsm[256];
    __shared__ int dim_[256];
    __shared__ double bsum[16];
    int t = threadIdx.x;
    int rr = blockIdx.x * 16 + (t >> 4);
    int j = t & 15;
    int c = cand[(size_t)rr * 16 + j];
    const float* row = C + (size_t)c * 256;
    int bl = rr >> 6, p = rr & 63;
    const float* xrow = fea + (size_t)bl * 16384 + p;
    double s = 0.0;
    for (int d = 0; d < 256; d++) {
        double diff = (double)xrow[d * 64] - (double)row[d];
        s = fma(diff, diff, s);
    }
    dsm[t] = s;
    dim_[t] = c;
    __syncthreads();
    if (j == 0) {
        double best = dsm[t]; int bi = dim_[t];
        for (int q = 1; q < 16; q++) {
            double v = dsm[t + q]; int ci = dim_[t + q];
            if (v < best || (v == best && ci < bi)) { best = v; bi = ci; }
        }
        enc[rr] = bi;
        bsum[t >> 4] = best;
    }
    __syncthreads();
    if (t == 0) {
        double acc = 0.0;
        for (int q = 0; q < 16; q++) acc += bsum[q];
        atomicAdd(dloss, acc);
    }
}

// ---------------- histogram ----------------
__global__ __launch_bounds__(256) void k_hist(const int* __restrict__ enc,
                                              int* __restrict__ counts) {
    __shared__ int hc[1024];
    for (int i = threadIdx.x; i < 1024; i += 256) hc[i] = 0;
    __syncthreads();
    int base = blockIdx.x * 1024;
    for (int i = threadIdx.x; i < 1024; i += 256) atomicAdd(&hc[enc[base + i]], 1);
    __syncthreads();
    for (int i = threadIdx.x; i < 1024; i += 256)
        if (hc[i]) atomicAdd(&counts[i], hc[i]);
}

// ---------------- Wt_bf[n][p][d] = bf16(fc1_w[n][d*64+p]) ----------------
__global__ __launch_bounds__(256) void k_wt(const float* __restrict__ W,
                                            unsigned short* __restrict__ Wt) {
    __shared__ float tile[64][65];
    int n = blockIdx.x;
    int d0 = blockIdx.y * 64;
    int t = threadIdx.x;
    const float* src = W + (size_t)n * 16384 + (size_t)d0 * 64;
#pragma unroll
    for (int u = 0; u < 4; u++) {
        int i = t + u * 256;
        float4 v = ((const float4*)src)[i];
        int dd = i >> 4;
        int p = (i & 15) << 2;
        tile[dd][p] = v.x; tile[dd][p + 1] = v.y; tile[dd][p + 2] = v.z; tile[dd][p + 3] = v.w;
    }
    __syncthreads();
    unsigned short* dst = Wt + (size_t)n * 16384 + d0;
#pragma unroll
    for (int u = 0; u < 4; u++) {
        int i = t + u * 256;
        int p = i >> 4;
        int dd = (i & 15) << 2;
        ushort4 v = { f2bf(tile[dd][p]), f2bf(tile[dd + 1][p]),
                      f2bf(tile[dd + 2][p]), f2bf(tile[dd + 3][p]) };
        *(ushort4*)(dst + (size_t)p * 256 + dd) = v;
    }
}

// ---------------- fc1 bf16 MFMA GEMM with gathered A, split-K z=8 ----------------
__global__ __launch_bounds__(256) void k_fc1g(const int* __restrict__ enc,
                                              const unsigned short* __restrict__ Cbf,
                                              const unsigned short* __restrict__ Wt,
                                              float* __restrict__ part) {
    __shared__ unsigned short As[128 * 32];
    __shared__ unsigned short Bs[128 * 32];
    __shared__ int encs[128];
    int t = threadIdx.x;
    int m0 = blockIdx.x * 128, n0 = blockIdx.y * 128;
    int L = t & 63, w = t >> 6;
    int quad = L >> 4, lc = L & 15;
    int mw = (w >> 1) * 64, nw = (w & 1) * 64;
    f32x4 acc[4][4];
#pragma unroll
    for (int i = 0; i < 4; i++)
#pragma unroll
        for (int j = 0; j < 4; j++) acc[i][j] = (f32x4){0.f, 0.f, 0.f, 0.f};
    int p0 = blockIdx.z * 8;
    for (int p = p0; p < p0 + 8; p++) {
        __syncthreads();
        if (t < 128) encs[t] = enc[(size_t)(m0 + t) * 64 + p];
        __syncthreads();
        for (int dseg = 0; dseg < 256; dseg += 32) {
#pragma unroll
            for (int u = 0; u < 2; u++) {
                int idx = t + u * 256;
                int m = idx >> 2, kq = idx & 3;
                const unsigned short* ga = Cbf + (size_t)encs[m] * 256 + dseg + kq * 8;
                *(uint4*)(As + m * 32 + kq * 8) = *(const uint4*)ga;
                const unsigned short* gb = Wt + (size_t)(n0 + m) * 16384 + p * 256 + dseg + kq * 8;
                *(uint4*)(Bs + m * 32 + kq * 8) = *(const uint4*)gb;
            }
            __syncthreads();
            short8 a[4], bv[4];
#pragma unroll
            for (int i = 0; i < 4; i++)
                a[i] = *(const short8*)(As + (mw + i * 16 + lc) * 32 + quad * 8);
#pragma unroll
            for (int j = 0; j < 4; j++)
                bv[j] = *(const short8*)(Bs + (nw + j * 16 + lc) * 32 + quad * 8);
#pragma unroll
            for (int i = 0; i < 4; i++)
#pragma unroll
                for (int j = 0; j < 4; j++)
                    acc[i][j] = __builtin_amdgcn_mfma_f32_16x16x32_bf16(a[i], bv[j], acc[i][j], 0, 0, 0);
            __syncthreads();
        }
    }
    float* P = part + (size_t)blockIdx.z * (2048 * 512);
#pragma unroll
    for (int i = 0; i < 4; i++)
#pragma unroll
        for (int j = 0; j < 4; j++)
#pragma unroll
            for (int reg = 0; reg < 4; reg++) {
                int row = m0 + mw + i * 16 + quad * 4 + reg;
                int col = n0 + nw + j * 16 + lc;
                P[(size_t)row * 512 + col] = acc[i][j][reg];
            }
}

__global__ __launch_bounds__(256) void k_fc1fin(const float* __restrict__ part,
                                                const float* __restrict__ bias,
                                                float* __restrict__ h1) {
    int i = blockIdx.x * 256 + threadIdx.x;
    float s = 0.f;
#pragma unroll
    for (int z = 0; z < 8; z++) s += part[i + (size_t)z * 1048576];
    s += bias[i & 511];
    h1[i] = 0.5f * s * (1.f + erff(s * 0.70710678118654752f));
}

// ---------------- fc2 ----------------
__global__ __launch_bounds__(256) void k_fc2(const float* __restrict__ h1,
                                             const float* __restrict__ w,
                                             const float* __restrict__ bias,
                                             float* __restrict__ out) {
    int gid = blockIdx.x * 256 + threadIdx.x;
    if (gid >= 20480) return;
    int b = gid / 10, k = gid % 10;
    const float* hr = h1 + (size_t)b * 512;
    const float* wr = w + (size_t)k * 512;
    float acc = bias[k];
#pragma unroll 8
    for (int j = 0; j < 512; j++) acc = fmaf(hr[j], wr[j], acc);
    out[gid] = acc;
}

// ---------------- loss + perplexity ----------------
__global__ __launch_bounds__(256) void k_final(const int* __restrict__ counts,
                                               const double* __restrict__ dloss,
                                               const int* __restrict__ idxp,
                                               float* __restrict__ out) {
    __shared__ float sb[256];
    int t = threadIdx.x;
    int Kc = (*idxp == 0) ? 512 : 1024;
    float local = 0.f;
    for (int c = t; c < Kc; c += 256) {
        float pr = (float)counts[c] * (1.0f / 131072.0f);
        local += pr * logf(pr + 1e-10f);
    }
    sb[t] = local;
    __syncthreads();
    for (int o = 128; o > 0; o >>= 1) {
        if (t < o) sb[t] += sb[t + o];
        __syncthreads();
    }
    if (t == 0) {
        out[20480] = (float)(dloss[0] * 1.25 / (131072.0 * 256.0));
        out[20481] = expf(-sb[0]);
    }
}

extern "C" void kernel_launch(void* const* d_in, const int* in_sizes, int n_in,
                              void* d_out, int out_size, void* d_ws, size_t ws_size,
                              hipStream_t stream) {
    const float* x    = (const float*)d_in[0];
    const int*   idxp = (const int*)d_in[1];
    const float* w1   = (const float*)d_in[2];
    const float* b1   = (const float*)d_in[3];
    const float* w2   = (const float*)d_in[4];
    const float* b2   = (const float*)d_in[5];
    const float* cb0  = (const float*)d_in[6];
    const float* cb1  = (const float*)d_in[7];
    const float* cb2  = (const float*)d_in[8];
    const float* fc1w = (const float*)d_in[9];
    const float* fc1b = (const float*)d_in[10];
    const float* fc2w = (const float*)d_in[11];
    const float* fc2b = (const float*)d_in[12];
    float* out = (float*)d_out;

    char* ws = (char*)d_ws;
    size_t off = 0;
    unsigned short* h_hi   = (unsigned short*)(ws + off); off += (size_t)CHUNK * 256 * 128 * 2; // 16.78 MB
    unsigned short* h_lo   = (unsigned short*)(ws + off); off += (size_t)CHUNK * 256 * 128 * 2; // 16.78 MB
    float*          fea_c  = (float*)(ws + off);          off += (size_t)CHUNK * 16384 * 4;     // 16.78 MB
    unsigned short* fea_bf = (unsigned short*)(ws + off); off += (size_t)CHUNK * 16384 * 2;     //  8.39 MB
    unsigned short* Wt_bf  = (unsigned short*)(ws + off); off += (size_t)512 * 16384 * 2;       // 16.78 MB
    unsigned short* Wc_hi  = (unsigned short*)(ws + off); off += (size_t)256 * 2048 * 2;        //  1.05 MB
    unsigned short* Wc_lo  = (unsigned short*)(ws + off); off += (size_t)256 * 2048 * 2;        //  1.05 MB
    float*          Cc     = (float*)(ws + off);          off += (size_t)1024 * 256 * 4;        //  1.05 MB
    unsigned short* Cc_bf  = (unsigned short*)(ws + off); off += (size_t)1024 * 256 * 2;        //  0.52 MB
    float*          h1     = (float*)(ws + off);          off += (size_t)2048 * 512 * 4;        //  4.19 MB
    int*            cand   = (int*)(ws + off);            off += (size_t)CHUNK * 64 * 16 * 4;   //  1.05 MB
    int*            enc    = (int*)(ws + off);            off += (size_t)131072 * 4;            //  0.52 MB
    float*          cnorm  = (float*)(ws + off);          off += 1024 * 4;
    int*            counts = (int*)(ws + off);            off += 1024 * 4;
    double*         dloss  = (double*)(ws + off);         off += 8;
    // total ~85 MB; part (8*2048*512*4 = 33.55 MB) aliases h_hi+h_lo (33.55 MB, dead after chunk loop)
    float* part = (float*)h_hi;

    hipMemsetAsync(counts, 0, 1024 * 4 + 8, stream);   // counts + dloss (contiguous)

    k_comb<<<256, 256, 0, stream>>>(cb0, cb1, cb2, idxp, Cc, Cc_bf);
    k_cnorm<<<4, 256, 0, stream>>>(Cc, idxp, cnorm);
    k_wt<<<dim3(512, 4), 256, 0, stream>>>(fc1w, Wt_bf);
    k_w2p<<<256, 256, 0, stream>>>(w2, Wc_hi, Wc_lo);

    for (int c = 0; c < NCH; c++) {
        k_conv1<<<CHUNK, 256, 0, stream>>>(x + (size_t)c * CHUNK * 3072, w1, b1, h_hi, h_lo);
        k_conv2m<<<dim3(CHUNK, 2), 256, 0, stream>>>(h_hi, h_lo, Wc_hi, Wc_lo, b2, fea_c, fea_bf);
        k_vqg<<<dim3(128, 8), 256, 0, stream>>>(fea_bf, Cc_bf, cnorm, cand);
        k_rescore<<<(CHUNK * 64) / 16, 256, 0, stream>>>(fea_c, Cc, cand,
                                                         enc + (size_t)c * CHUNK * 64, dloss);
    }

    k_hist<<<128, 256, 0, stream>>>(enc, counts);
    k_fc1g<<<dim3(16, 4, 8), 256, 0, stream>>>(enc, Cc_bf, Wt_bf, part);
    k_fc1fin<<<4096, 256, 0, stream>>>(part, fc1b, h1);
    k_fc2<<<80, 256, 0, stream>>>(h1, fc2w, fc2b, out);
    k_final<<<1, 256, 0, stream>>>(counts, dloss, idxp, out);
}